// Round 18
// baseline (233.553 us; speedup 1.0000x reference)
//
#include <hip/hip_runtime.h>
#include <math.h>

#define BB 8
#define CC 32
#define NN 4096
#define KNN 32
#define NP (BB*NN)   // 32768

// workspace float offsets
#define OFF_XT  0u
#define OFF_QF  1048576u
#define OFF_KV  2097152u   // 2M floats: 32 x float2 per point
#define OFF_XX  4194304u
#define OFF_IDX 4227072u   // 1M u32
#define OFF_XH  5275648u   // 1M f16
#define OFF_MSG 5799936u   // 1M floats

typedef _Float16 f16x8 __attribute__((ext_vector_type(8)));
typedef float f32x4 __attribute__((ext_vector_type(4)));
#define MFMA16(A,B,C) __builtin_amdgcn_mfma_f32_16x16x32_f16(A,B,C,0,0,0)

__device__ __forceinline__ float elu1(float x) {
    return x > 0.f ? x + 1.f : expf(x);
}

// ---------------- K1: transpose feat[B,C,N] -> xt[B,N,C] + Xh/xx ----------------
__global__ __launch_bounds__(256) void k_transpose(const float* __restrict__ feat,
                                                   float* __restrict__ xt,
                                                   _Float16* __restrict__ Xh,
                                                   float* __restrict__ xx) {
    __shared__ float tile[32][65];
    int b = blockIdx.y;
    int n0 = blockIdx.x * 64;
    int t = threadIdx.x;
    int nn = t & 63, cr = t >> 6;
#pragma unroll
    for (int r = 0; r < 8; ++r) {
        int c = r * 4 + cr;
        tile[c][nn] = feat[((size_t)b * 32 + c) * NN + n0 + nn];
    }
    __syncthreads();
    int c2 = t & 31, nr = t >> 5;
#pragma unroll
    for (int r = 0; r < 8; ++r) {
        int nl = r * 8 + nr;
        size_t gi = ((size_t)b * NN + n0 + nl) * 32 + c2;
        float v = tile[c2][nl];
        xt[gi] = v;
        Xh[gi] = (_Float16)v;
    }
    if (t < 64) {
        float s = 0.f;
#pragma unroll
        for (int c = 0; c < 32; ++c) { float u = tile[c][t]; s += u * u; }
        xx[(size_t)b * NN + n0 + t] = s;
    }
}

// ---------------- K2: per-point prep (weights in LDS) ----------------
__global__ __launch_bounds__(256, 2) void k_prep(
        const float* __restrict__ xt, const float* __restrict__ xyz,
        const float* __restrict__ w_pos1, const float* __restrict__ b_pos1,
        const float* __restrict__ w_pos2, const float* __restrict__ b_pos2,
        const float* __restrict__ w_q, const float* __restrict__ w_k,
        const float* __restrict__ w_v,
        float* __restrict__ Qf, float* __restrict__ KV) {
    __shared__ float sW2[1024], sWq[1024], sWk[1024], sWv[1024];
    int t = threadIdx.x;
    for (int i = t; i < 1024; i += 256) {
        sW2[i] = w_pos2[i];
        sWq[i] = w_q[i];
        sWk[i] = w_k[i];
        sWv[i] = w_v[i];
    }
    int lane = t & 31;
    int g = t >> 5;
    float w1c0 = w_pos1[lane], w1c1 = w_pos1[32 + lane], w1c2 = w_pos1[64 + lane];
    float b1c = b_pos1[lane], b2c = b_pos2[lane];
    __syncthreads();
#pragma unroll 1
    for (int p = blockIdx.x * 8 + g; p < NP; p += gridDim.x * 8) {
        asm volatile("" ::: "memory");
        float x0 = xyz[(size_t)p * 3 + 0];
        float x1 = xyz[(size_t)p * 3 + 1];
        float x2 = xyz[(size_t)p * 3 + 2];
        float h = fmaxf(x0 * w1c0 + x1 * w1c1 + x2 * w1c2 + b1c, 0.f);
        float P = b2c;
#pragma unroll 8
        for (int j = 0; j < 32; ++j) P += __shfl(h, j, 32) * sW2[j * 32 + lane];
        float xv = xt[(size_t)p * 32 + lane];
        float qin = xv + P;
        float qa = 0.f, ka = 0.f, va = 0.f;
#pragma unroll 8
        for (int j = 0; j < 32; ++j) {
            float qj = __shfl(qin, j, 32);
            qa += qj * sWq[j * 32 + lane];
            ka += qj * sWk[j * 32 + lane];
            va += qj * sWv[j * 32 + lane];
        }
        Qf[(size_t)p * 32 + lane] = elu1(qa);
        float2 kvv;
        kvv.x = elu1(ka);
        kvv.y = va;   // raw V ((V/k)*k cancels exactly)
        *(((float2*)(KV + (size_t)p * 64)) + lane) = kvv;
    }
}

// ---------------- K3: KNN — r14 algorithm; stride 132 + tie 64 (29.9 KB) ----------
// Selection math identical to the verified-exact r14 kernel. LDS layout: histogram
// stride 132 words (rows rotate banks by 4 — measured lower conflicts than 129),
// tieIdx 64 entries (margin window holds ~7+-3/row; >15 sigma headroom).
__global__ __launch_bounds__(256, 4) void k_knn(
        const _Float16* __restrict__ Xh,
        const float* __restrict__ xt, const float* __restrict__ xx,
        unsigned* __restrict__ idxg) {
    __shared__ unsigned histU[32 * 132];   // 16.9 KB
    __shared__ unsigned outIdx[32][32];    // 4 KB
    __shared__ unsigned tieIdx[32][64];    // 8 KB
    __shared__ int sT[32];
    __shared__ float sFloor[32];
    __shared__ unsigned outCnt[32], tieCnt[32];
    __shared__ float sM2;
    __shared__ float redbuf[4];

    int bid = blockIdx.x;
    int b = bid & 7;                 // XCD swizzle: batch per XCD
    int n0 = (bid >> 3) << 5;        // 32 rows per block
    int t = threadIdx.x;
    int lane = t & 63, wv = t >> 6;
    size_t bbase = (size_t)b * NN;

    for (int i = t; i < 32 * 132; i += 256) histU[i] = 0u;
    if (t < 32) { outCnt[t] = 0u; tieCnt[t] = 0u; }

    float lm = 0.f;
    for (int i = t; i < NN; i += 256) lm = fmaxf(lm, xx[bbase + i]);
#pragma unroll
    for (int off = 32; off >= 1; off >>= 1) lm = fmaxf(lm, __shfl_xor(lm, off, 64));
    if (lane == 0) redbuf[wv] = lm;
    __syncthreads();
    if (t == 0) sM2 = fmaxf(fmaxf(redbuf[0], redbuf[1]), fmaxf(redbuf[2], redbuf[3]));
    __syncthreads();
    float M2 = sM2;

    int al = lane & 15;
    int kgrp = lane >> 4;
    int ak = kgrp * 8;
    const _Float16* Xhb = Xh + bbase * 32;
    const float* xxb = xx + bbase;
    f16x8 Ah0 = *(const f16x8*)(Xhb + (size_t)(n0 + al) * 32 + ak);
    f16x8 Ah1 = *(const f16x8*)(Xhb + (size_t)(n0 + 16 + al) * 32 + ak);

    const float C127 = 127.99f;
    float sc2[8], scn[8], c0a[8];
    unsigned rowW[8];
    int rowloc8[8];
#pragma unroll
    for (int r = 0; r < 8; ++r) {
        int rowloc = (r < 4 ? 0 : 16) + kgrp * 4 + (r & 3);
        float xxi = xxb[n0 + rowloc];
        float scale = C127 / (2.f * (xxi + M2));
        sc2[r] = scale + scale;
        scn[r] = -scale;
        c0a[r] = __builtin_fmaf(-xxi, scale, C127);
        rowW[r] = (unsigned)rowloc * 132u;
        rowloc8[r] = rowloc;
    }

    unsigned cp0 = (unsigned)(wv * 1024 + al);
    unsigned akB = (unsigned)ak * 2u;
    const char* XhbB = (const char*)Xhb;
    const f32x4 z = {0.f, 0.f, 0.f, 0.f};

    // ---- phase A: full histogram of first 8 tiles (512-col sample) ----
#pragma unroll 1
    for (int tt = 0; tt < 8; ++tt) {
        unsigned cp = cp0 + (unsigned)(tt << 4);
        f16x8 Bh = *(const f16x8*)(XhbB + cp * 64u + akB);
        float xxj = xxb[cp];
        f32x4 a0 = MFMA16(Ah0, Bh, z);
        f32x4 a1 = MFMA16(Ah1, Bh, z);
#pragma unroll
        for (int r = 0; r < 8; ++r) {
            float a = (r < 4) ? a0[r] : a1[r - 4];
            float bcol = __builtin_fmaf(xxj, scn[r], c0a[r]);
            float qf = __builtin_fmaf(a, sc2[r], bcol);
            float qc = __builtin_amdgcn_fmed3f(qf, 0.f, C127);
            atomicAdd(&histU[rowW[r] + (unsigned)qc], 1u);
        }
    }
    __syncthreads();

    // ---- floor scan: per-row 32nd-best bucket of the sample ----
#pragma unroll 1
    for (int rr = 0; rr < 8; ++rr) {
        int row = wv * 8 + rr;
        const unsigned* Hr = histU + row * 132;
        unsigned cl = Hr[2 * lane], ch = Hr[2 * lane + 1];
        unsigned ss = cl + ch;
        unsigned acc = ss;
#pragma unroll
        for (int off = 1; off < 64; off <<= 1) {
            unsigned vv = __shfl_down(acc, off, 64);
            if (lane + off < 64) acc += vv;
        }
        unsigned run = acc - ss;
        int Tl = -1;
        if (run < 32u && run + ch >= 32u) Tl = 2 * lane + 1;
        run += ch;
        if (Tl < 0 && run < 32u && run + cl >= 32u) Tl = 2 * lane;
        unsigned long long bal = __ballot(Tl >= 0);
        int src = __ffsll(bal) - 1;
        int Tv = __shfl(Tl, src, 64);
        if (lane == 0) sFloor[row] = (Tv <= 0) ? -3.0e38f : (float)Tv;
    }
    __syncthreads();

    float fb1[8];
#pragma unroll
    for (int r = 0; r < 8; ++r) fb1[r] = sFloor[rowloc8[r]];

    // ---- phase B: filtered histogram of tiles 8..63 (pipelined) ----
    {
        unsigned cpc = cp0 + (8u << 4);
        f16x8 Bh_c = *(const f16x8*)(XhbB + cpc * 64u + akB);
        float xxj_c = xxb[cpc];
#pragma unroll 1
        for (int tt = 8; tt < 64; ++tt) {
            int tn = (tt + 1 < 64) ? (tt + 1) : 8;
            unsigned cpn = cp0 + (unsigned)(tn << 4);
            f16x8 Bh_n = *(const f16x8*)(XhbB + cpn * 64u + akB);
            float xxj_n = xxb[cpn];
            f32x4 a0 = MFMA16(Ah0, Bh_c, z);
            f32x4 a1 = MFMA16(Ah1, Bh_c, z);
            float bcol[8];
#pragma unroll
            for (int r = 0; r < 8; ++r) bcol[r] = __builtin_fmaf(xxj_c, scn[r], c0a[r]);
#pragma unroll
            for (int r = 0; r < 8; ++r) {
                float a = (r < 4) ? a0[r] : a1[r - 4];
                float qf = __builtin_fmaf(a, sc2[r], bcol[r]);
                if (qf >= fb1[r]) {
                    float qc = __builtin_amdgcn_fmed3f(qf, 0.f, C127);
                    atomicAdd(&histU[rowW[r] + (unsigned)qc], 1u);
                }
            }
            Bh_c = Bh_n; xxj_c = xxj_n;
        }
    }
    __syncthreads();

    // ---- final scan: per-row suffix over 128 buckets -> T ----
#pragma unroll 1
    for (int rr = 0; rr < 8; ++rr) {
        int row = wv * 8 + rr;
        const unsigned* Hr = histU + row * 132;
        unsigned cl = Hr[2 * lane], ch = Hr[2 * lane + 1];
        unsigned ss = cl + ch;
        unsigned acc = ss;
#pragma unroll
        for (int off = 1; off < 64; off <<= 1) {
            unsigned vv = __shfl_down(acc, off, 64);
            if (lane + off < 64) acc += vv;
        }
        unsigned run = acc - ss;
        int Tl = -1;
        if (run < 32u && run + ch >= 32u) Tl = 2 * lane + 1;
        run += ch;
        if (Tl < 0 && run < 32u && run + cl >= 32u) Tl = 2 * lane;
        unsigned long long bal = __ballot(Tl >= 0);
        int src = __ffsll(bal) - 1;
        int Tv = __shfl(Tl, src, 64);
        if (lane == 0) sT[row] = Tv;
    }
    __syncthreads();

    // margin thresholds: certain qf >= T+1+m; candidate qf >= T-m (m = 0.1875 >= 3*eps)
    float Tin[8], Tlo[8];
#pragma unroll
    for (int r = 0; r < 8; ++r) {
        int T = sT[rowloc8[r]];
        Tin[r] = (float)(T + 1) + 0.1875f;
        Tlo[r] = (T == 0) ? -3.0e38f : ((float)T - 0.1875f);
    }

    // ---- sweep 2: identical qf recompute, margin-window emit ----
    {
        f16x8 Bh_c = *(const f16x8*)(XhbB + cp0 * 64u + akB);
        float xxj_c = xxb[cp0];
#pragma unroll 1
        for (int tt = 0; tt < 64; ++tt) {
            unsigned cp = cp0 + (unsigned)(tt << 4);
            unsigned cpn = cp0 + (unsigned)(((tt + 1) & 63) << 4);
            f16x8 Bh_n = *(const f16x8*)(XhbB + cpn * 64u + akB);
            float xxj_n = xxb[cpn];
            f32x4 a0 = MFMA16(Ah0, Bh_c, z);
            f32x4 a1 = MFMA16(Ah1, Bh_c, z);
            float bcol[8];
#pragma unroll
            for (int r = 0; r < 8; ++r) bcol[r] = __builtin_fmaf(xxj_c, scn[r], c0a[r]);
#pragma unroll
            for (int r = 0; r < 8; ++r) {
                float a = (r < 4) ? a0[r] : a1[r - 4];
                float qf = __builtin_fmaf(a, sc2[r], bcol[r]);
                if (qf >= Tlo[r]) {
                    unsigned row = (unsigned)rowloc8[r];
                    if (qf >= Tin[r]) {
                        unsigned pos = atomicAdd(&outCnt[row], 1u);
                        outIdx[row][pos] = cp;
                    } else {
                        unsigned tp = atomicAdd(&tieCnt[row], 1u);
                        if (tp < 64u) tieIdx[row][tp] = cp;
                    }
                }
            }
            Bh_c = Bh_n; xxj_c = xxj_n;
        }
    }
    __syncthreads();

    // ---- resolve candidate window with exact fp32 scores (nt <= 64: 1 slot/lane) ----
#pragma unroll 1
    for (int rr = 0; rr < 8; ++rr) {
        int row = wv * 8 + rr;
        int gr = n0 + row;
        unsigned bA = outCnt[row];
        int need = 32 - (int)bA;
        if (need <= 0) continue;
        int nt = (int)tieCnt[row]; if (nt > 64) nt = 64;
        const float* xr = xt + (bbase + gr) * 32;
        float xxi_r = xxb[gr];
        float v0 = -INFINITY;
        int i0 = 0x7fffffff;
        bool a0v = lane < nt;
        if (a0v) {
            int c = (int)tieIdx[row][lane];
            const float* xc = xt + (bbase + c) * 32;
            float dot = 0.f;
#pragma unroll
            for (int ch = 0; ch < 32; ch += 4) {
                float4 rv = *(const float4*)(xr + ch);
                float4 cv = *(const float4*)(xc + ch);
                dot = __builtin_fmaf(rv.x, cv.x, dot);
                dot = __builtin_fmaf(rv.y, cv.y, dot);
                dot = __builtin_fmaf(rv.z, cv.z, dot);
                dot = __builtin_fmaf(rv.w, cv.w, dot);
            }
            v0 = 2.f * dot - xxi_r - xxb[c];
            i0 = c;
        }
        for (int it = 0; it < need; ++it) {
            float bvv = a0v ? v0 : -INFINITY;
            int bj2 = a0v ? i0 : 0x7fffffff;
#pragma unroll
            for (int off = 1; off < 64; off <<= 1) {
                float ov = __shfl_xor(bvv, off, 64);
                int oj = __shfl_xor(bj2, off, 64);
                if (ov > bvv || (ov == bvv && oj < bj2)) { bvv = ov; bj2 = oj; }
            }
            if (a0v && i0 == bj2) a0v = false;
            if (lane == 0) outIdx[row][bA + it] = (unsigned)bj2;
        }
    }
    __syncthreads();

    for (int i = t; i < 1024; i += 256)
        idxg[(bbase + n0 + (i >> 5)) * 32 + (i & 31)] = outIdx[i >> 5][i & 31];
}

// ---------------- K4: attention gather only -> msg (XCD-swizzled) ----------------
__global__ __launch_bounds__(256) void k_attn(
        const float* __restrict__ Qf, const float* __restrict__ KV,
        const unsigned* __restrict__ idxg, float* __restrict__ msg) {
    int t = threadIdx.x;
    int wv = t >> 6, lane = t & 63;
    int l32 = lane & 31;
    int bid = blockIdx.x;
    int b = bid & 7;                  // XCD k serves batch k's 1MB KV from its L2
    int p = b * NN + (bid >> 3) * 8 + wv * 2 + (lane >> 5);
    size_t bbase = (size_t)b * NN;
    const char* KVb = (const char*)(KV + bbase * 64);
    float q = Qf[(size_t)p * 32 + l32];
    int jv = (int)idxg[(size_t)p * 32 + l32];
    unsigned laneoff = (unsigned)l32 * 8u;
    float zacc = 0.f, macc = 0.f;
#pragma unroll 8
    for (int k = 0; k < 32; ++k) {
        int j = __shfl(jv, k, 32);
        unsigned off = ((unsigned)j << 8) + laneoff;
        float2 kv = *(const float2*)(KVb + off);
        float s = q * kv.x;
        s += __shfl_xor(s, 1, 8);
        s += __shfl_xor(s, 2, 8);
        s += __shfl_xor(s, 4, 8);
        zacc += s;
        macc = __builtin_fmaf(s, kv.y, macc);
    }
    float Z = 1.f / (zacc + 1e-6f);
    msg[(size_t)p * 32 + l32] = macc * Z;
}

// ---------------- K5: merge + LN1 + MLP + LN2 + residual + transpose (MFMA) ----------------
__global__ __launch_bounds__(256, 2) void k_post(
        const float* __restrict__ msg, const float* __restrict__ xt,
        const float* __restrict__ w_merge,
        const float* __restrict__ ln1_g, const float* __restrict__ ln1_b,
        const float* __restrict__ w_mlp1, const float* __restrict__ w_mlp2,
        const float* __restrict__ ln2_g, const float* __restrict__ ln2_b,
        float* __restrict__ out) {
    __shared__ _Float16 wmT[2][32][32];
    __shared__ _Float16 w1T[2][64][64];
    __shared__ _Float16 w2T[2][32][64];
    __shared__ _Float16 sPh[4][16][40], sPl[4][16][40];
    __shared__ _Float16 sHh[4][16][72], sHl[4][16][72];
    int t = threadIdx.x;
    for (int i = t; i < 1024; i += 256) {
        float v = w_merge[i]; int in = i >> 5, o = i & 31;
        _Float16 h = (_Float16)v;
        wmT[0][o][in] = h; wmT[1][o][in] = (_Float16)(v - (float)h);
    }
    for (int i = t; i < 4096; i += 256) {
        float v = w_mlp1[i]; int in = i >> 6, o = i & 63;
        _Float16 h = (_Float16)v;
        w1T[0][o][in] = h; w1T[1][o][in] = (_Float16)(v - (float)h);
    }
    for (int i = t; i < 2048; i += 256) {
        float v = w_mlp2[i]; int in = i >> 5, o = i & 31;
        _Float16 h = (_Float16)v;
        w2T[0][o][in] = h; w2T[1][o][in] = (_Float16)(v - (float)h);
    }
    int wv = t >> 6, lane = t & 63;
    int row = lane & 15, kg = lane >> 4;
    int p0 = blockIdx.x * 64 + wv * 16;
    int b = p0 >> 12;
    float g1a = ln1_g[row], b1a = ln1_b[row], g1b = ln1_g[row + 16], b1b = ln1_b[row + 16];
    float g2a = ln2_g[row], b2a = ln2_b[row], g2b = ln2_g[row + 16], b2b = ln2_b[row + 16];
    __syncthreads();

    f32x4 z4 = {0.f, 0.f, 0.f, 0.f};
    f16x8 Amh, Aml;
    {
        const float* mr = msg + (size_t)(p0 + row) * 32 + kg * 8;
#pragma unroll
        for (int j = 0; j < 8; ++j) {
            float v = mr[j];
            _Float16 h = (_Float16)v;
            Amh[j] = h; Aml[j] = (_Float16)(v - (float)h);
        }
    }
    f32x4 accM[2];
#pragma unroll
    for (int n = 0; n < 2; ++n) {
        f16x8 Bh = *(const f16x8*)&wmT[0][n * 16 + row][kg * 8];
        f16x8 Bl = *(const f16x8*)&wmT[1][n * 16 + row][kg * 8];
        f32x4 a = z4;
        a = MFMA16(Aml, Bl, a); a = MFMA16(Amh, Bl, a);
        a = MFMA16(Aml, Bh, a); a = MFMA16(Amh, Bh, a);
        accM[n] = a;
    }
#pragma unroll
    for (int r = 0; r < 4; ++r) {
        float s0 = accM[0][r], s1 = accM[1][r];
        float sm = s0 + s1;
        sm += __shfl_xor(sm, 1, 64); sm += __shfl_xor(sm, 2, 64);
        sm += __shfl_xor(sm, 4, 64); sm += __shfl_xor(sm, 8, 64);
        float mean = sm * (1.f / 32.f);
        float d0 = s0 - mean, d1 = s1 - mean;
        float vv = d0 * d0 + d1 * d1;
        vv += __shfl_xor(vv, 1, 64); vv += __shfl_xor(vv, 2, 64);
        vv += __shfl_xor(vv, 4, 64); vv += __shfl_xor(vv, 8, 64);
        float rst = rsqrtf(vv * (1.f / 32.f) + 1e-5f);
        float m0 = g1a * d0 * rst + b1a;
        float m1 = g1b * d1 * rst + b1b;
        int pl = kg * 4 + r;
        _Float16 h0 = (_Float16)m0;
        sPh[wv][pl][row] = h0; sPl[wv][pl][row] = (_Float16)(m0 - (float)h0);
        _Float16 h1 = (_Float16)m1;
        sPh[wv][pl][row + 16] = h1; sPl[wv][pl][row + 16] = (_Float16)(m1 - (float)h1);
    }
    __syncthreads();
    f16x8 Axh, Axl;
    {
        const float* xr = xt + (size_t)(p0 + row) * 32 + kg * 8;
#pragma unroll
        for (int j = 0; j < 8; ++j) {
            float v = xr[j];
            _Float16 h = (_Float16)v;
            Axh[j] = h; Axl[j] = (_Float16)(v - (float)h);
        }
    }
    f16x8 Aph = *(const f16x8*)&sPh[wv][row][kg * 8];
    f16x8 Apl = *(const f16x8*)&sPl[wv][row][kg * 8];
    f32x4 accH[4];
#pragma unroll
    for (int n = 0; n < 4; ++n) {
        f16x8 B0h = *(const f16x8*)&w1T[0][n * 16 + row][kg * 8];
        f16x8 B0l = *(const f16x8*)&w1T[1][n * 16 + row][kg * 8];
        f16x8 B1h = *(const f16x8*)&w1T[0][n * 16 + row][32 + kg * 8];
        f16x8 B1l = *(const f16x8*)&w1T[1][n * 16 + row][32 + kg * 8];
        f32x4 a = z4;
        a = MFMA16(Axl, B0l, a); a = MFMA16(Axh, B0l, a);
        a = MFMA16(Axl, B0h, a); a = MFMA16(Axh, B0h, a);
        a = MFMA16(Apl, B1l, a); a = MFMA16(Aph, B1l, a);
        a = MFMA16(Apl, B1h, a); a = MFMA16(Aph, B1h, a);
        accH[n] = a;
    }
#pragma unroll
    for (int n = 0; n < 4; ++n) {
#pragma unroll
        for (int r = 0; r < 4; ++r) {
            float hv = fmaxf(accH[n][r], 0.f);
            int pl = kg * 4 + r;
            _Float16 hh = (_Float16)hv;
            sHh[wv][pl][n * 16 + row] = hh;
            sHl[wv][pl][n * 16 + row] = (_Float16)(hv - (float)hh);
        }
    }
    __syncthreads();
    f16x8 Hh0 = *(const f16x8*)&sHh[wv][row][kg * 8];
    f16x8 Hl0 = *(const f16x8*)&sHl[wv][row][kg * 8];
    f16x8 Hh1 = *(const f16x8*)&sHh[wv][row][32 + kg * 8];
    f16x8 Hl1 = *(const f16x8*)&sHl[wv][row][32 + kg * 8];
    f32x4 accO[2];
#pragma unroll
    for (int n = 0; n < 2; ++n) {
        f16x8 B0h = *(const f16x8*)&w2T[0][n * 16 + row][kg * 8];
        f16x8 B0l = *(const f16x8*)&w2T[1][n * 16 + row][kg * 8];
        f16x8 B1h = *(const f16x8*)&w2T[0][n * 16 + row][32 + kg * 8];
        f16x8 B1l = *(const f16x8*)&w2T[1][n * 16 + row][32 + kg * 8];
        f32x4 a = z4;
        a = MFMA16(Hl0, B0l, a); a = MFMA16(Hh0, B0l, a);
        a = MFMA16(Hl0, B0h, a); a = MFMA16(Hh0, B0h, a);
        a = MFMA16(Hl1, B1l, a); a = MFMA16(Hh1, B1l, a);
        a = MFMA16(Hl1, B1h, a); a = MFMA16(Hh1, B1h, a);
        accO[n] = a;
    }
#pragma unroll
    for (int r = 0; r < 4; ++r) {
        float s0 = accO[0][r], s1 = accO[1][r];
        float sm = s0 + s1;
        sm += __shfl_xor(sm, 1, 64); sm += __shfl_xor(sm, 2, 64);
        sm += __shfl_xor(sm, 4, 64); sm += __shfl_xor(sm, 8, 64);
        float mean = sm * (1.f / 32.f);
        float d0 = s0 - mean, d1 = s1 - mean;
        float vv = d0 * d0 + d1 * d1;
        vv += __shfl_xor(vv, 1, 64); vv += __shfl_xor(vv, 2, 64);
        vv += __shfl_xor(vv, 4, 64); vv += __shfl_xor(vv, 8, 64);
        float rst = rsqrtf(vv * (1.f / 32.f) + 1e-5f);
        float o0 = g2a * d0 * rst + b2a;
        float o1 = g2b * d1 * rst + b2b;
        int pt = p0 + kg * 4 + r;
        int nb = pt & 4095;
        float xv0 = xt[(size_t)pt * 32 + row];
        float xv1 = xt[(size_t)pt * 32 + row + 16];
        out[((size_t)b * 32 + row) * 4096 + nb] = xv0 + o0;
        out[((size_t)b * 32 + row + 16) * 4096 + nb] = xv1 + o1;
    }
}

extern "C" void kernel_launch(void* const* d_in, const int* in_sizes, int n_in,
                              void* d_out, int out_size, void* d_ws, size_t ws_size,
                              hipStream_t stream) {
    const float* feat   = (const float*)d_in[0];
    const float* xyz    = (const float*)d_in[1];
    const float* w_pos1 = (const float*)d_in[2];
    const float* b_pos1 = (const float*)d_in[3];
    const float* w_pos2 = (const float*)d_in[4];
    const float* b_pos2 = (const float*)d_in[5];
    const float* w_q    = (const float*)d_in[6];
    const float* w_k    = (const float*)d_in[7];
    const float* w_v    = (const float*)d_in[8];
    const float* w_mg   = (const float*)d_in[9];
    const float* ln1_g  = (const float*)d_in[10];
    const float* ln1_b  = (const float*)d_in[11];
    const float* w_mlp1 = (const float*)d_in[12];
    const float* w_mlp2 = (const float*)d_in[13];
    const float* ln2_g  = (const float*)d_in[14];
    const float* ln2_b  = (const float*)d_in[15];
    float* ws = (float*)d_ws;
    float* xt = ws + OFF_XT;
    float* Qf = ws + OFF_QF;
    float* KVp = ws + OFF_KV;
    float* xx = ws + OFF_XX;
    unsigned* idxg = (unsigned*)(ws + OFF_IDX);
    _Float16* Xh = (_Float16*)(ws + OFF_XH);
    float* msg = ws + OFF_MSG;
    float* out = (float*)d_out;

    k_transpose<<<dim3(64, 8), 256, 0, stream>>>(feat, xt, Xh, xx);
    k_prep<<<1024, 256, 0, stream>>>(xt, xyz, w_pos1, b_pos1, w_pos2, b_pos2,
                                     w_q, w_k, w_v, Qf, KVp);
    k_knn<<<1024, 256, 0, stream>>>(Xh, xt, xx, idxg);
    k_attn<<<4096, 256, 0, stream>>>(Qf, KVp, idxg, msg);
    k_post<<<512, 256, 0, stream>>>(msg, xt, w_mg, ln1_g, ln1_b,
                                    w_mlp1, w_mlp2, ln2_g, ln2_b, out);
}

// Round 19
// 225.516 us; speedup vs baseline: 1.0356x; 1.0356x over previous
//
#include <hip/hip_runtime.h>
#include <math.h>

#define BB 8
#define CC 32
#define NN 4096
#define KNN 32
#define NP (BB*NN)   // 32768

// workspace float offsets
#define OFF_XT  0u
#define OFF_QF  1048576u
#define OFF_KV  2097152u   // 2M floats: 32 x float2 per point
#define OFF_XX  4194304u
#define OFF_XH  5275648u   // 1M f16
#define OFF_MSG 5799936u   // 1M floats

typedef _Float16 f16x8 __attribute__((ext_vector_type(8)));
typedef float f32x4 __attribute__((ext_vector_type(4)));
#define MFMA16(A,B,C) __builtin_amdgcn_mfma_f32_16x16x32_f16(A,B,C,0,0,0)

__device__ __forceinline__ float elu1(float x) {
    return x > 0.f ? x + 1.f : expf(x);
}

// ---------------- K1: transpose feat[B,C,N] -> xt[B,N,C] + Xh/xx ----------------
__global__ __launch_bounds__(256) void k_transpose(const float* __restrict__ feat,
                                                   float* __restrict__ xt,
                                                   _Float16* __restrict__ Xh,
                                                   float* __restrict__ xx) {
    __shared__ float tile[32][65];
    int b = blockIdx.y;
    int n0 = blockIdx.x * 64;
    int t = threadIdx.x;
    int nn = t & 63, cr = t >> 6;
#pragma unroll
    for (int r = 0; r < 8; ++r) {
        int c = r * 4 + cr;
        tile[c][nn] = feat[((size_t)b * 32 + c) * NN + n0 + nn];
    }
    __syncthreads();
    int c2 = t & 31, nr = t >> 5;
#pragma unroll
    for (int r = 0; r < 8; ++r) {
        int nl = r * 8 + nr;
        size_t gi = ((size_t)b * NN + n0 + nl) * 32 + c2;
        float v = tile[c2][nl];
        xt[gi] = v;
        Xh[gi] = (_Float16)v;
    }
    if (t < 64) {
        float s = 0.f;
#pragma unroll
        for (int c = 0; c < 32; ++c) { float u = tile[c][t]; s += u * u; }
        xx[(size_t)b * NN + n0 + t] = s;
    }
}

// ---------------- K2: per-point prep (weights in LDS) ----------------
__global__ __launch_bounds__(256, 2) void k_prep(
        const float* __restrict__ xt, const float* __restrict__ xyz,
        const float* __restrict__ w_pos1, const float* __restrict__ b_pos1,
        const float* __restrict__ w_pos2, const float* __restrict__ b_pos2,
        const float* __restrict__ w_q, const float* __restrict__ w_k,
        const float* __restrict__ w_v,
        float* __restrict__ Qf, float* __restrict__ KV) {
    __shared__ float sW2[1024], sWq[1024], sWk[1024], sWv[1024];
    int t = threadIdx.x;
    for (int i = t; i < 1024; i += 256) {
        sW2[i] = w_pos2[i];
        sWq[i] = w_q[i];
        sWk[i] = w_k[i];
        sWv[i] = w_v[i];
    }
    int lane = t & 31;
    int g = t >> 5;
    float w1c0 = w_pos1[lane], w1c1 = w_pos1[32 + lane], w1c2 = w_pos1[64 + lane];
    float b1c = b_pos1[lane], b2c = b_pos2[lane];
    __syncthreads();
#pragma unroll 1
    for (int p = blockIdx.x * 8 + g; p < NP; p += gridDim.x * 8) {
        asm volatile("" ::: "memory");
        float x0 = xyz[(size_t)p * 3 + 0];
        float x1 = xyz[(size_t)p * 3 + 1];
        float x2 = xyz[(size_t)p * 3 + 2];
        float h = fmaxf(x0 * w1c0 + x1 * w1c1 + x2 * w1c2 + b1c, 0.f);
        float P = b2c;
#pragma unroll 8
        for (int j = 0; j < 32; ++j) P += __shfl(h, j, 32) * sW2[j * 32 + lane];
        float xv = xt[(size_t)p * 32 + lane];
        float qin = xv + P;
        float qa = 0.f, ka = 0.f, va = 0.f;
#pragma unroll 8
        for (int j = 0; j < 32; ++j) {
            float qj = __shfl(qin, j, 32);
            qa += qj * sWq[j * 32 + lane];
            ka += qj * sWk[j * 32 + lane];
            va += qj * sWv[j * 32 + lane];
        }
        Qf[(size_t)p * 32 + lane] = elu1(qa);
        float2 kvv;
        kvv.x = elu1(ka);
        kvv.y = va;   // raw V ((V/k)*k cancels exactly)
        *(((float2*)(KV + (size_t)p * 64)) + lane) = kvv;
    }
}

// ---------------- K3: KNN + fused attention gather ----------
// Selection math identical to the verified-exact r14/r18 kernel (stride 132,
// tie 64). New: the k_attn gather is fused at the tail — each wave computes the
// per-head linear-attention message for its 8 rows using outIdx straight from
// LDS (no idxg round-trip, no separate launch; gather overlaps other blocks'
// compute phases). Attention sums over the neighbor SET (order-invariant up to
// fp rounding, same as the previous idxg-mediated path).
__global__ __launch_bounds__(256, 4) void k_knn(
        const _Float16* __restrict__ Xh,
        const float* __restrict__ xt, const float* __restrict__ xx,
        const float* __restrict__ Qf, const float* __restrict__ KV,
        float* __restrict__ msg) {
    __shared__ unsigned histU[32 * 132];   // 16.9 KB
    __shared__ unsigned outIdx[32][32];    // 4 KB
    __shared__ unsigned tieIdx[32][64];    // 8 KB
    __shared__ int sT[32];
    __shared__ float sFloor[32];
    __shared__ unsigned outCnt[32], tieCnt[32];
    __shared__ float sM2;
    __shared__ float redbuf[4];

    int bid = blockIdx.x;
    int b = bid & 7;                 // XCD swizzle: batch per XCD
    int n0 = (bid >> 3) << 5;        // 32 rows per block
    int t = threadIdx.x;
    int lane = t & 63, wv = t >> 6;
    size_t bbase = (size_t)b * NN;

    for (int i = t; i < 32 * 132; i += 256) histU[i] = 0u;
    if (t < 32) { outCnt[t] = 0u; tieCnt[t] = 0u; }

    float lm = 0.f;
    for (int i = t; i < NN; i += 256) lm = fmaxf(lm, xx[bbase + i]);
#pragma unroll
    for (int off = 32; off >= 1; off >>= 1) lm = fmaxf(lm, __shfl_xor(lm, off, 64));
    if (lane == 0) redbuf[wv] = lm;
    __syncthreads();
    if (t == 0) sM2 = fmaxf(fmaxf(redbuf[0], redbuf[1]), fmaxf(redbuf[2], redbuf[3]));
    __syncthreads();
    float M2 = sM2;

    int al = lane & 15;
    int kgrp = lane >> 4;
    int ak = kgrp * 8;
    const _Float16* Xhb = Xh + bbase * 32;
    const float* xxb = xx + bbase;
    f16x8 Ah0 = *(const f16x8*)(Xhb + (size_t)(n0 + al) * 32 + ak);
    f16x8 Ah1 = *(const f16x8*)(Xhb + (size_t)(n0 + 16 + al) * 32 + ak);

    const float C127 = 127.99f;
    float sc2[8], scn[8], c0a[8];
    unsigned rowW[8];
    int rowloc8[8];
#pragma unroll
    for (int r = 0; r < 8; ++r) {
        int rowloc = (r < 4 ? 0 : 16) + kgrp * 4 + (r & 3);
        float xxi = xxb[n0 + rowloc];
        float scale = C127 / (2.f * (xxi + M2));
        sc2[r] = scale + scale;
        scn[r] = -scale;
        c0a[r] = __builtin_fmaf(-xxi, scale, C127);
        rowW[r] = (unsigned)rowloc * 132u;
        rowloc8[r] = rowloc;
    }

    unsigned cp0 = (unsigned)(wv * 1024 + al);
    unsigned akB = (unsigned)ak * 2u;
    const char* XhbB = (const char*)Xhb;
    const f32x4 z = {0.f, 0.f, 0.f, 0.f};

    // ---- phase A: full histogram of first 8 tiles (512-col sample) ----
#pragma unroll 1
    for (int tt = 0; tt < 8; ++tt) {
        unsigned cp = cp0 + (unsigned)(tt << 4);
        f16x8 Bh = *(const f16x8*)(XhbB + cp * 64u + akB);
        float xxj = xxb[cp];
        f32x4 a0 = MFMA16(Ah0, Bh, z);
        f32x4 a1 = MFMA16(Ah1, Bh, z);
#pragma unroll
        for (int r = 0; r < 8; ++r) {
            float a = (r < 4) ? a0[r] : a1[r - 4];
            float bcol = __builtin_fmaf(xxj, scn[r], c0a[r]);
            float qf = __builtin_fmaf(a, sc2[r], bcol);
            float qc = __builtin_amdgcn_fmed3f(qf, 0.f, C127);
            atomicAdd(&histU[rowW[r] + (unsigned)qc], 1u);
        }
    }
    __syncthreads();

    // ---- floor scan: per-row 32nd-best bucket of the sample ----
#pragma unroll 1
    for (int rr = 0; rr < 8; ++rr) {
        int row = wv * 8 + rr;
        const unsigned* Hr = histU + row * 132;
        unsigned cl = Hr[2 * lane], ch = Hr[2 * lane + 1];
        unsigned ss = cl + ch;
        unsigned acc = ss;
#pragma unroll
        for (int off = 1; off < 64; off <<= 1) {
            unsigned vv = __shfl_down(acc, off, 64);
            if (lane + off < 64) acc += vv;
        }
        unsigned run = acc - ss;
        int Tl = -1;
        if (run < 32u && run + ch >= 32u) Tl = 2 * lane + 1;
        run += ch;
        if (Tl < 0 && run < 32u && run + cl >= 32u) Tl = 2 * lane;
        unsigned long long bal = __ballot(Tl >= 0);
        int src = __ffsll(bal) - 1;
        int Tv = __shfl(Tl, src, 64);
        if (lane == 0) sFloor[row] = (Tv <= 0) ? -3.0e38f : (float)Tv;
    }
    __syncthreads();

    float fb1[8];
#pragma unroll
    for (int r = 0; r < 8; ++r) fb1[r] = sFloor[rowloc8[r]];

    // ---- phase B: filtered histogram of tiles 8..63 (pipelined) ----
    {
        unsigned cpc = cp0 + (8u << 4);
        f16x8 Bh_c = *(const f16x8*)(XhbB + cpc * 64u + akB);
        float xxj_c = xxb[cpc];
#pragma unroll 1
        for (int tt = 8; tt < 64; ++tt) {
            int tn = (tt + 1 < 64) ? (tt + 1) : 8;
            unsigned cpn = cp0 + (unsigned)(tn << 4);
            f16x8 Bh_n = *(const f16x8*)(XhbB + cpn * 64u + akB);
            float xxj_n = xxb[cpn];
            f32x4 a0 = MFMA16(Ah0, Bh_c, z);
            f32x4 a1 = MFMA16(Ah1, Bh_c, z);
            float bcol[8];
#pragma unroll
            for (int r = 0; r < 8; ++r) bcol[r] = __builtin_fmaf(xxj_c, scn[r], c0a[r]);
#pragma unroll
            for (int r = 0; r < 8; ++r) {
                float a = (r < 4) ? a0[r] : a1[r - 4];
                float qf = __builtin_fmaf(a, sc2[r], bcol[r]);
                if (qf >= fb1[r]) {
                    float qc = __builtin_amdgcn_fmed3f(qf, 0.f, C127);
                    atomicAdd(&histU[rowW[r] + (unsigned)qc], 1u);
                }
            }
            Bh_c = Bh_n; xxj_c = xxj_n;
        }
    }
    __syncthreads();

    // ---- final scan: per-row suffix over 128 buckets -> T ----
#pragma unroll 1
    for (int rr = 0; rr < 8; ++rr) {
        int row = wv * 8 + rr;
        const unsigned* Hr = histU + row * 132;
        unsigned cl = Hr[2 * lane], ch = Hr[2 * lane + 1];
        unsigned ss = cl + ch;
        unsigned acc = ss;
#pragma unroll
        for (int off = 1; off < 64; off <<= 1) {
            unsigned vv = __shfl_down(acc, off, 64);
            if (lane + off < 64) acc += vv;
        }
        unsigned run = acc - ss;
        int Tl = -1;
        if (run < 32u && run + ch >= 32u) Tl = 2 * lane + 1;
        run += ch;
        if (Tl < 0 && run < 32u && run + cl >= 32u) Tl = 2 * lane;
        unsigned long long bal = __ballot(Tl >= 0);
        int src = __ffsll(bal) - 1;
        int Tv = __shfl(Tl, src, 64);
        if (lane == 0) sT[row] = Tv;
    }
    __syncthreads();

    // margin thresholds: certain qf >= T+1+m; candidate qf >= T-m (m = 0.1875 >= 3*eps)
    float Tin[8], Tlo[8];
#pragma unroll
    for (int r = 0; r < 8; ++r) {
        int T = sT[rowloc8[r]];
        Tin[r] = (float)(T + 1) + 0.1875f;
        Tlo[r] = (T == 0) ? -3.0e38f : ((float)T - 0.1875f);
    }

    // ---- sweep 2: identical qf recompute, margin-window emit ----
    {
        f16x8 Bh_c = *(const f16x8*)(XhbB + cp0 * 64u + akB);
        float xxj_c = xxb[cp0];
#pragma unroll 1
        for (int tt = 0; tt < 64; ++tt) {
            unsigned cp = cp0 + (unsigned)(tt << 4);
            unsigned cpn = cp0 + (unsigned)(((tt + 1) & 63) << 4);
            f16x8 Bh_n = *(const f16x8*)(XhbB + cpn * 64u + akB);
            float xxj_n = xxb[cpn];
            f32x4 a0 = MFMA16(Ah0, Bh_c, z);
            f32x4 a1 = MFMA16(Ah1, Bh_c, z);
            float bcol[8];
#pragma unroll
            for (int r = 0; r < 8; ++r) bcol[r] = __builtin_fmaf(xxj_c, scn[r], c0a[r]);
#pragma unroll
            for (int r = 0; r < 8; ++r) {
                float a = (r < 4) ? a0[r] : a1[r - 4];
                float qf = __builtin_fmaf(a, sc2[r], bcol[r]);
                if (qf >= Tlo[r]) {
                    unsigned row = (unsigned)rowloc8[r];
                    if (qf >= Tin[r]) {
                        unsigned pos = atomicAdd(&outCnt[row], 1u);
                        outIdx[row][pos] = cp;
                    } else {
                        unsigned tp = atomicAdd(&tieCnt[row], 1u);
                        if (tp < 64u) tieIdx[row][tp] = cp;
                    }
                }
            }
            Bh_c = Bh_n; xxj_c = xxj_n;
        }
    }
    __syncthreads();

    // ---- resolve candidate window with exact fp32 scores (nt <= 64: 1 slot/lane) ----
#pragma unroll 1
    for (int rr = 0; rr < 8; ++rr) {
        int row = wv * 8 + rr;
        int gr = n0 + row;
        unsigned bA = outCnt[row];
        int need = 32 - (int)bA;
        if (need <= 0) continue;
        int nt = (int)tieCnt[row]; if (nt > 64) nt = 64;
        const float* xr = xt + (bbase + gr) * 32;
        float xxi_r = xxb[gr];
        float v0 = -INFINITY;
        int i0 = 0x7fffffff;
        bool a0v = lane < nt;
        if (a0v) {
            int c = (int)tieIdx[row][lane];
            const float* xc = xt + (bbase + c) * 32;
            float dot = 0.f;
#pragma unroll
            for (int ch = 0; ch < 32; ch += 4) {
                float4 rv = *(const float4*)(xr + ch);
                float4 cv = *(const float4*)(xc + ch);
                dot = __builtin_fmaf(rv.x, cv.x, dot);
                dot = __builtin_fmaf(rv.y, cv.y, dot);
                dot = __builtin_fmaf(rv.z, cv.z, dot);
                dot = __builtin_fmaf(rv.w, cv.w, dot);
            }
            v0 = 2.f * dot - xxi_r - xxb[c];
            i0 = c;
        }
        for (int it = 0; it < need; ++it) {
            float bvv = a0v ? v0 : -INFINITY;
            int bj2 = a0v ? i0 : 0x7fffffff;
#pragma unroll
            for (int off = 1; off < 64; off <<= 1) {
                float ov = __shfl_xor(bvv, off, 64);
                int oj = __shfl_xor(bj2, off, 64);
                if (ov > bvv || (ov == bvv && oj < bj2)) { bvv = ov; bj2 = oj; }
            }
            if (a0v && i0 == bj2) a0v = false;
            if (lane == 0) outIdx[row][bA + it] = (unsigned)bj2;
        }
    }
    __syncthreads();

    // ---- fused attention gather (replaces the k_attn kernel) ----
    {
        int l32 = lane & 31;
        int hsel = lane >> 5;                 // which of the 2 rows this half handles
        const char* KVb = (const char*)(KV + bbase * 64);
        unsigned laneoff = (unsigned)l32 * 8u;
#pragma unroll 1
        for (int rr = 0; rr < 4; ++rr) {
            int row = wv * 8 + rr * 2 + hsel;
            size_t gp = bbase + (size_t)(n0 + row);
            float q = Qf[gp * 32 + l32];
            int jv = (int)outIdx[row][l32];   // lane l32 holds neighbor index l32
            float zacc = 0.f, macc = 0.f;
#pragma unroll 8
            for (int k = 0; k < 32; ++k) {
                int j = __shfl(jv, k, 32);
                unsigned off = ((unsigned)j << 8) + laneoff;
                float2 kv = *(const float2*)(KVb + off);
                float s = q * kv.x;
                s += __shfl_xor(s, 1, 8);
                s += __shfl_xor(s, 2, 8);
                s += __shfl_xor(s, 4, 8);
                zacc += s;
                macc = __builtin_fmaf(s, kv.y, macc);
            }
            float Z = 1.f / (zacc + 1e-6f);
            msg[gp * 32 + l32] = macc * Z;
        }
    }
}

// ---------------- K5: merge + LN1 + MLP + LN2 + residual + transpose (MFMA) ----------------
__global__ __launch_bounds__(256, 2) void k_post(
        const float* __restrict__ msg, const float* __restrict__ xt,
        const float* __restrict__ w_merge,
        const float* __restrict__ ln1_g, const float* __restrict__ ln1_b,
        const float* __restrict__ w_mlp1, const float* __restrict__ w_mlp2,
        const float* __restrict__ ln2_g, const float* __restrict__ ln2_b,
        float* __restrict__ out) {
    __shared__ _Float16 wmT[2][32][32];
    __shared__ _Float16 w1T[2][64][64];
    __shared__ _Float16 w2T[2][32][64];
    __shared__ _Float16 sPh[4][16][40], sPl[4][16][40];
    __shared__ _Float16 sHh[4][16][72], sHl[4][16][72];
    int t = threadIdx.x;
    for (int i = t; i < 1024; i += 256) {
        float v = w_merge[i]; int in = i >> 5, o = i & 31;
        _Float16 h = (_Float16)v;
        wmT[0][o][in] = h; wmT[1][o][in] = (_Float16)(v - (float)h);
    }
    for (int i = t; i < 4096; i += 256) {
        float v = w_mlp1[i]; int in = i >> 6, o = i & 63;
        _Float16 h = (_Float16)v;
        w1T[0][o][in] = h; w1T[1][o][in] = (_Float16)(v - (float)h);
    }
    for (int i = t; i < 2048; i += 256) {
        float v = w_mlp2[i]; int in = i >> 5, o = i & 31;
        _Float16 h = (_Float16)v;
        w2T[0][o][in] = h; w2T[1][o][in] = (_Float16)(v - (float)h);
    }
    int wv = t >> 6, lane = t & 63;
    int row = lane & 15, kg = lane >> 4;
    int p0 = blockIdx.x * 64 + wv * 16;
    int b = p0 >> 12;
    float g1a = ln1_g[row], b1a = ln1_b[row], g1b = ln1_g[row + 16], b1b = ln1_b[row + 16];
    float g2a = ln2_g[row], b2a = ln2_b[row], g2b = ln2_g[row + 16], b2b = ln2_b[row + 16];
    __syncthreads();

    f32x4 z4 = {0.f, 0.f, 0.f, 0.f};
    f16x8 Amh, Aml;
    {
        const float* mr = msg + (size_t)(p0 + row) * 32 + kg * 8;
#pragma unroll
        for (int j = 0; j < 8; ++j) {
            float v = mr[j];
            _Float16 h = (_Float16)v;
            Amh[j] = h; Aml[j] = (_Float16)(v - (float)h);
        }
    }
    f32x4 accM[2];
#pragma unroll
    for (int n = 0; n < 2; ++n) {
        f16x8 Bh = *(const f16x8*)&wmT[0][n * 16 + row][kg * 8];
        f16x8 Bl = *(const f16x8*)&wmT[1][n * 16 + row][kg * 8];
        f32x4 a = z4;
        a = MFMA16(Aml, Bl, a); a = MFMA16(Amh, Bl, a);
        a = MFMA16(Aml, Bh, a); a = MFMA16(Amh, Bh, a);
        accM[n] = a;
    }
#pragma unroll
    for (int r = 0; r < 4; ++r) {
        float s0 = accM[0][r], s1 = accM[1][r];
        float sm = s0 + s1;
        sm += __shfl_xor(sm, 1, 64); sm += __shfl_xor(sm, 2, 64);
        sm += __shfl_xor(sm, 4, 64); sm += __shfl_xor(sm, 8, 64);
        float mean = sm * (1.f / 32.f);
        float d0 = s0 - mean, d1 = s1 - mean;
        float vv = d0 * d0 + d1 * d1;
        vv += __shfl_xor(vv, 1, 64); vv += __shfl_xor(vv, 2, 64);
        vv += __shfl_xor(vv, 4, 64); vv += __shfl_xor(vv, 8, 64);
        float rst = rsqrtf(vv * (1.f / 32.f) + 1e-5f);
        float m0 = g1a * d0 * rst + b1a;
        float m1 = g1b * d1 * rst + b1b;
        int pl = kg * 4 + r;
        _Float16 h0 = (_Float16)m0;
        sPh[wv][pl][row] = h0; sPl[wv][pl][row] = (_Float16)(m0 - (float)h0);
        _Float16 h1 = (_Float16)m1;
        sPh[wv][pl][row + 16] = h1; sPl[wv][pl][row + 16] = (_Float16)(m1 - (float)h1);
    }
    __syncthreads();
    f16x8 Axh, Axl;
    {
        const float* xr = xt + (size_t)(p0 + row) * 32 + kg * 8;
#pragma unroll
        for (int j = 0; j < 8; ++j) {
            float v = xr[j];
            _Float16 h = (_Float16)v;
            Axh[j] = h; Axl[j] = (_Float16)(v - (float)h);
        }
    }
    f16x8 Aph = *(const f16x8*)&sPh[wv][row][kg * 8];
    f16x8 Apl = *(const f16x8*)&sPl[wv][row][kg * 8];
    f32x4 accH[4];
#pragma unroll
    for (int n = 0; n < 4; ++n) {
        f16x8 B0h = *(const f16x8*)&w1T[0][n * 16 + row][kg * 8];
        f16x8 B0l = *(const f16x8*)&w1T[1][n * 16 + row][kg * 8];
        f16x8 B1h = *(const f16x8*)&w1T[0][n * 16 + row][32 + kg * 8];
        f16x8 B1l = *(const f16x8*)&w1T[1][n * 16 + row][32 + kg * 8];
        f32x4 a = z4;
        a = MFMA16(Axl, B0l, a); a = MFMA16(Axh, B0l, a);
        a = MFMA16(Axl, B0h, a); a = MFMA16(Axh, B0h, a);
        a = MFMA16(Apl, B1l, a); a = MFMA16(Aph, B1l, a);
        a = MFMA16(Apl, B1h, a); a = MFMA16(Aph, B1h, a);
        accH[n] = a;
    }
#pragma unroll
    for (int n = 0; n < 4; ++n) {
#pragma unroll
        for (int r = 0; r < 4; ++r) {
            float hv = fmaxf(accH[n][r], 0.f);
            int pl = kg * 4 + r;
            _Float16 hh = (_Float16)hv;
            sHh[wv][pl][n * 16 + row] = hh;
            sHl[wv][pl][n * 16 + row] = (_Float16)(hv - (float)hh);
        }
    }
    __syncthreads();
    f16x8 Hh0 = *(const f16x8*)&sHh[wv][row][kg * 8];
    f16x8 Hl0 = *(const f16x8*)&sHl[wv][row][kg * 8];
    f16x8 Hh1 = *(const f16x8*)&sHh[wv][row][32 + kg * 8];
    f16x8 Hl1 = *(const f16x8*)&sHl[wv][row][32 + kg * 8];
    f32x4 accO[2];
#pragma unroll
    for (int n = 0; n < 2; ++n) {
        f16x8 B0h = *(const f16x8*)&w2T[0][n * 16 + row][kg * 8];
        f16x8 B0l = *(const f16x8*)&w2T[1][n * 16 + row][kg * 8];
        f16x8 B1h = *(const f16x8*)&w2T[0][n * 16 + row][32 + kg * 8];
        f16x8 B1l = *(const f16x8*)&w2T[1][n * 16 + row][32 + kg * 8];
        f32x4 a = z4;
        a = MFMA16(Hl0, B0l, a); a = MFMA16(Hh0, B0l, a);
        a = MFMA16(Hl0, B0h, a); a = MFMA16(Hh0, B0h, a);
        a = MFMA16(Hl1, B1l, a); a = MFMA16(Hh1, B1l, a);
        a = MFMA16(Hl1, B1h, a); a = MFMA16(Hh1, B1h, a);
        accO[n] = a;
    }
#pragma unroll
    for (int r = 0; r < 4; ++r) {
        float s0 = accO[0][r], s1 = accO[1][r];
        float sm = s0 + s1;
        sm += __shfl_xor(sm, 1, 64); sm += __shfl_xor(sm, 2, 64);
        sm += __shfl_xor(sm, 4, 64); sm += __shfl_xor(sm, 8, 64);
        float mean = sm * (1.f / 32.f);
        float d0 = s0 - mean, d1 = s1 - mean;
        float vv = d0 * d0 + d1 * d1;
        vv += __shfl_xor(vv, 1, 64); vv += __shfl_xor(vv, 2, 64);
        vv += __shfl_xor(vv, 4, 64); vv += __shfl_xor(vv, 8, 64);
        float rst = rsqrtf(vv * (1.f / 32.f) + 1e-5f);
        float o0 = g2a * d0 * rst + b2a;
        float o1 = g2b * d1 * rst + b2b;
        int pt = p0 + kg * 4 + r;
        int nb = pt & 4095;
        float xv0 = xt[(size_t)pt * 32 + row];
        float xv1 = xt[(size_t)pt * 32 + row + 16];
        out[((size_t)b * 32 + row) * 4096 + nb] = xv0 + o0;
        out[((size_t)b * 32 + row + 16) * 4096 + nb] = xv1 + o1;
    }
}

extern "C" void kernel_launch(void* const* d_in, const int* in_sizes, int n_in,
                              void* d_out, int out_size, void* d_ws, size_t ws_size,
                              hipStream_t stream) {
    const float* feat   = (const float*)d_in[0];
    const float* xyz    = (const float*)d_in[1];
    const float* w_pos1 = (const float*)d_in[2];
    const float* b_pos1 = (const float*)d_in[3];
    const float* w_pos2 = (const float*)d_in[4];
    const float* b_pos2 = (const float*)d_in[5];
    const float* w_q    = (const float*)d_in[6];
    const float* w_k    = (const float*)d_in[7];
    const float* w_v    = (const float*)d_in[8];
    const float* w_mg   = (const float*)d_in[9];
    const float* ln1_g  = (const float*)d_in[10];
    const float* ln1_b  = (const float*)d_in[11];
    const float* w_mlp1 = (const float*)d_in[12];
    const float* w_mlp2 = (const float*)d_in[13];
    const float* ln2_g  = (const float*)d_in[14];
    const float* ln2_b  = (const float*)d_in[15];
    float* ws = (float*)d_ws;
    float* xt = ws + OFF_XT;
    float* Qf = ws + OFF_QF;
    float* KVp = ws + OFF_KV;
    float* xx = ws + OFF_XX;
    _Float16* Xh = (_Float16*)(ws + OFF_XH);
    float* msg = ws + OFF_MSG;
    float* out = (float*)d_out;

    k_transpose<<<dim3(64, 8), 256, 0, stream>>>(feat, xt, Xh, xx);
    k_prep<<<1024, 256, 0, stream>>>(xt, xyz, w_pos1, b_pos1, w_pos2, b_pos2,
                                     w_q, w_k, w_v, Qf, KVp);
    k_knn<<<1024, 256, 0, stream>>>(Xh, xt, xx, Qf, KVp, msg);
    k_post<<<512, 256, 0, stream>>>(msg, xt, w_mg, ln1_g, ln1_b,
                                    w_mlp1, w_mlp2, ln2_g, ln2_b, out);
}

// Round 20
// 220.760 us; speedup vs baseline: 1.0580x; 1.0215x over previous
//
#include <hip/hip_runtime.h>
#include <math.h>

#define BB 8
#define CC 32
#define NN 4096
#define KNN 32
#define NP (BB*NN)   // 32768

// workspace float offsets
#define OFF_XT  0u
#define OFF_QF  1048576u
#define OFF_KV  2097152u   // 2M floats: 32 x float2 per point
#define OFF_XX  4194304u
#define OFF_XH  5275648u   // 1M f16
#define OFF_MSG 5799936u   // 1M floats

typedef _Float16 f16x8 __attribute__((ext_vector_type(8)));
typedef float f32x4 __attribute__((ext_vector_type(4)));
#define MFMA16(A,B,C) __builtin_amdgcn_mfma_f32_16x16x32_f16(A,B,C,0,0,0)

__device__ __forceinline__ float elu1(float x) {
    return x > 0.f ? x + 1.f : expf(x);
}

// ---------------- K1: fused transpose + prep ----------------
// feat[B,C,N] -> xt[B,N,C], Xh (f16), xx (row norms), and per-point prep
// (pos-MLP + Q/K/V projections -> Qf, KV) reading xv straight from the LDS tile.
__global__ __launch_bounds__(256) void k_tp(
        const float* __restrict__ feat, const float* __restrict__ xyz,
        const float* __restrict__ w_pos1, const float* __restrict__ b_pos1,
        const float* __restrict__ w_pos2, const float* __restrict__ b_pos2,
        const float* __restrict__ w_q, const float* __restrict__ w_k,
        const float* __restrict__ w_v,
        float* __restrict__ xt, _Float16* __restrict__ Xh,
        float* __restrict__ xx,
        float* __restrict__ Qf, float* __restrict__ KV) {
    __shared__ float tile[32][65];                       // 8.3 KB
    __shared__ float sW2[1024], sWq[1024], sWk[1024], sWv[1024];  // 16 KB
    int b = blockIdx.y;
    int n0 = blockIdx.x * 64;
    int t = threadIdx.x;

    for (int i = t; i < 1024; i += 256) {
        sW2[i] = w_pos2[i];
        sWq[i] = w_q[i];
        sWk[i] = w_k[i];
        sWv[i] = w_v[i];
    }
    int lane = t & 31;
    float w1c0 = w_pos1[lane], w1c1 = w_pos1[32 + lane], w1c2 = w_pos1[64 + lane];
    float b1c = b_pos1[lane], b2c = b_pos2[lane];

    int nn = t & 63, cr = t >> 6;
#pragma unroll
    for (int r = 0; r < 8; ++r) {
        int c = r * 4 + cr;
        tile[c][nn] = feat[((size_t)b * 32 + c) * NN + n0 + nn];
    }
    __syncthreads();

    // transposed stores + f16 copy
    int c2 = t & 31, nr = t >> 5;
#pragma unroll
    for (int r = 0; r < 8; ++r) {
        int nl = r * 8 + nr;
        size_t gi = ((size_t)b * NN + n0 + nl) * 32 + c2;
        float v = tile[c2][nl];
        xt[gi] = v;
        Xh[gi] = (_Float16)v;
    }
    // row norms
    if (t < 64) {
        float s = 0.f;
#pragma unroll
        for (int c = 0; c < 32; ++c) { float u = tile[c][t]; s += u * u; }
        xx[(size_t)b * NN + n0 + t] = s;
    }

    // per-point prep: 8 groups of 32 lanes, 8 points each
    int g = t >> 5;
#pragma unroll 1
    for (int pp = g; pp < 64; pp += 8) {
        asm volatile("" ::: "memory");   // keep LDS weight reads inside the loop
        size_t p = (size_t)b * NN + n0 + pp;
        float x0 = xyz[p * 3 + 0];
        float x1 = xyz[p * 3 + 1];
        float x2 = xyz[p * 3 + 2];
        float h = fmaxf(x0 * w1c0 + x1 * w1c1 + x2 * w1c2 + b1c, 0.f);
        float P = b2c;
#pragma unroll 8
        for (int j = 0; j < 32; ++j) P += __shfl(h, j, 32) * sW2[j * 32 + lane];
        float xv = tile[lane][pp];       // bank-free column read
        float qin = xv + P;
        float qa = 0.f, ka = 0.f, va = 0.f;
#pragma unroll 8
        for (int j = 0; j < 32; ++j) {
            float qj = __shfl(qin, j, 32);
            qa += qj * sWq[j * 32 + lane];
            ka += qj * sWk[j * 32 + lane];
            va += qj * sWv[j * 32 + lane];
        }
        Qf[p * 32 + lane] = elu1(qa);
        float2 kvv;
        kvv.x = elu1(ka);
        kvv.y = va;   // raw V ((V/k)*k cancels exactly)
        *(((float2*)(KV + p * 64)) + lane) = kvv;
    }
}

// ---------------- K3: KNN + fused attention gather (r19, unchanged) ----------
__global__ __launch_bounds__(256, 4) void k_knn(
        const _Float16* __restrict__ Xh,
        const float* __restrict__ xt, const float* __restrict__ xx,
        const float* __restrict__ Qf, const float* __restrict__ KV,
        float* __restrict__ msg) {
    __shared__ unsigned histU[32 * 132];   // 16.9 KB
    __shared__ unsigned outIdx[32][32];    // 4 KB
    __shared__ unsigned tieIdx[32][64];    // 8 KB
    __shared__ int sT[32];
    __shared__ float sFloor[32];
    __shared__ unsigned outCnt[32], tieCnt[32];
    __shared__ float sM2;
    __shared__ float redbuf[4];

    int bid = blockIdx.x;
    int b = bid & 7;                 // XCD swizzle: batch per XCD
    int n0 = (bid >> 3) << 5;        // 32 rows per block
    int t = threadIdx.x;
    int lane = t & 63, wv = t >> 6;
    size_t bbase = (size_t)b * NN;

    for (int i = t; i < 32 * 132; i += 256) histU[i] = 0u;
    if (t < 32) { outCnt[t] = 0u; tieCnt[t] = 0u; }

    float lm = 0.f;
    for (int i = t; i < NN; i += 256) lm = fmaxf(lm, xx[bbase + i]);
#pragma unroll
    for (int off = 32; off >= 1; off >>= 1) lm = fmaxf(lm, __shfl_xor(lm, off, 64));
    if (lane == 0) redbuf[wv] = lm;
    __syncthreads();
    if (t == 0) sM2 = fmaxf(fmaxf(redbuf[0], redbuf[1]), fmaxf(redbuf[2], redbuf[3]));
    __syncthreads();
    float M2 = sM2;

    int al = lane & 15;
    int kgrp = lane >> 4;
    int ak = kgrp * 8;
    const _Float16* Xhb = Xh + bbase * 32;
    const float* xxb = xx + bbase;
    f16x8 Ah0 = *(const f16x8*)(Xhb + (size_t)(n0 + al) * 32 + ak);
    f16x8 Ah1 = *(const f16x8*)(Xhb + (size_t)(n0 + 16 + al) * 32 + ak);

    const float C127 = 127.99f;
    float sc2[8], scn[8], c0a[8];
    unsigned rowW[8];
    int rowloc8[8];
#pragma unroll
    for (int r = 0; r < 8; ++r) {
        int rowloc = (r < 4 ? 0 : 16) + kgrp * 4 + (r & 3);
        float xxi = xxb[n0 + rowloc];
        float scale = C127 / (2.f * (xxi + M2));
        sc2[r] = scale + scale;
        scn[r] = -scale;
        c0a[r] = __builtin_fmaf(-xxi, scale, C127);
        rowW[r] = (unsigned)rowloc * 132u;
        rowloc8[r] = rowloc;
    }

    unsigned cp0 = (unsigned)(wv * 1024 + al);
    unsigned akB = (unsigned)ak * 2u;
    const char* XhbB = (const char*)Xhb;
    const f32x4 z = {0.f, 0.f, 0.f, 0.f};

    // ---- phase A: full histogram of first 8 tiles (512-col sample) ----
#pragma unroll 1
    for (int tt = 0; tt < 8; ++tt) {
        unsigned cp = cp0 + (unsigned)(tt << 4);
        f16x8 Bh = *(const f16x8*)(XhbB + cp * 64u + akB);
        float xxj = xxb[cp];
        f32x4 a0 = MFMA16(Ah0, Bh, z);
        f32x4 a1 = MFMA16(Ah1, Bh, z);
#pragma unroll
        for (int r = 0; r < 8; ++r) {
            float a = (r < 4) ? a0[r] : a1[r - 4];
            float bcol = __builtin_fmaf(xxj, scn[r], c0a[r]);
            float qf = __builtin_fmaf(a, sc2[r], bcol);
            float qc = __builtin_amdgcn_fmed3f(qf, 0.f, C127);
            atomicAdd(&histU[rowW[r] + (unsigned)qc], 1u);
        }
    }
    __syncthreads();

    // ---- floor scan: per-row 32nd-best bucket of the sample ----
#pragma unroll 1
    for (int rr = 0; rr < 8; ++rr) {
        int row = wv * 8 + rr;
        const unsigned* Hr = histU + row * 132;
        unsigned cl = Hr[2 * lane], ch = Hr[2 * lane + 1];
        unsigned ss = cl + ch;
        unsigned acc = ss;
#pragma unroll
        for (int off = 1; off < 64; off <<= 1) {
            unsigned vv = __shfl_down(acc, off, 64);
            if (lane + off < 64) acc += vv;
        }
        unsigned run = acc - ss;
        int Tl = -1;
        if (run < 32u && run + ch >= 32u) Tl = 2 * lane + 1;
        run += ch;
        if (Tl < 0 && run < 32u && run + cl >= 32u) Tl = 2 * lane;
        unsigned long long bal = __ballot(Tl >= 0);
        int src = __ffsll(bal) - 1;
        int Tv = __shfl(Tl, src, 64);
        if (lane == 0) sFloor[row] = (Tv <= 0) ? -3.0e38f : (float)Tv;
    }
    __syncthreads();

    float fb1[8];
#pragma unroll
    for (int r = 0; r < 8; ++r) fb1[r] = sFloor[rowloc8[r]];

    // ---- phase B: filtered histogram of tiles 8..63 (pipelined) ----
    {
        unsigned cpc = cp0 + (8u << 4);
        f16x8 Bh_c = *(const f16x8*)(XhbB + cpc * 64u + akB);
        float xxj_c = xxb[cpc];
#pragma unroll 1
        for (int tt = 8; tt < 64; ++tt) {
            int tn = (tt + 1 < 64) ? (tt + 1) : 8;
            unsigned cpn = cp0 + (unsigned)(tn << 4);
            f16x8 Bh_n = *(const f16x8*)(XhbB + cpn * 64u + akB);
            float xxj_n = xxb[cpn];
            f32x4 a0 = MFMA16(Ah0, Bh_c, z);
            f32x4 a1 = MFMA16(Ah1, Bh_c, z);
            float bcol[8];
#pragma unroll
            for (int r = 0; r < 8; ++r) bcol[r] = __builtin_fmaf(xxj_c, scn[r], c0a[r]);
#pragma unroll
            for (int r = 0; r < 8; ++r) {
                float a = (r < 4) ? a0[r] : a1[r - 4];
                float qf = __builtin_fmaf(a, sc2[r], bcol[r]);
                if (qf >= fb1[r]) {
                    float qc = __builtin_amdgcn_fmed3f(qf, 0.f, C127);
                    atomicAdd(&histU[rowW[r] + (unsigned)qc], 1u);
                }
            }
            Bh_c = Bh_n; xxj_c = xxj_n;
        }
    }
    __syncthreads();

    // ---- final scan: per-row suffix over 128 buckets -> T ----
#pragma unroll 1
    for (int rr = 0; rr < 8; ++rr) {
        int row = wv * 8 + rr;
        const unsigned* Hr = histU + row * 132;
        unsigned cl = Hr[2 * lane], ch = Hr[2 * lane + 1];
        unsigned ss = cl + ch;
        unsigned acc = ss;
#pragma unroll
        for (int off = 1; off < 64; off <<= 1) {
            unsigned vv = __shfl_down(acc, off, 64);
            if (lane + off < 64) acc += vv;
        }
        unsigned run = acc - ss;
        int Tl = -1;
        if (run < 32u && run + ch >= 32u) Tl = 2 * lane + 1;
        run += ch;
        if (Tl < 0 && run < 32u && run + cl >= 32u) Tl = 2 * lane;
        unsigned long long bal = __ballot(Tl >= 0);
        int src = __ffsll(bal) - 1;
        int Tv = __shfl(Tl, src, 64);
        if (lane == 0) sT[row] = Tv;
    }
    __syncthreads();

    // margin thresholds: certain qf >= T+1+m; candidate qf >= T-m (m = 0.1875 >= 3*eps)
    float Tin[8], Tlo[8];
#pragma unroll
    for (int r = 0; r < 8; ++r) {
        int T = sT[rowloc8[r]];
        Tin[r] = (float)(T + 1) + 0.1875f;
        Tlo[r] = (T == 0) ? -3.0e38f : ((float)T - 0.1875f);
    }

    // ---- sweep 2: identical qf recompute, margin-window emit ----
    {
        f16x8 Bh_c = *(const f16x8*)(XhbB + cp0 * 64u + akB);
        float xxj_c = xxb[cp0];
#pragma unroll 1
        for (int tt = 0; tt < 64; ++tt) {
            unsigned cp = cp0 + (unsigned)(tt << 4);
            unsigned cpn = cp0 + (unsigned)(((tt + 1) & 63) << 4);
            f16x8 Bh_n = *(const f16x8*)(XhbB + cpn * 64u + akB);
            float xxj_n = xxb[cpn];
            f32x4 a0 = MFMA16(Ah0, Bh_c, z);
            f32x4 a1 = MFMA16(Ah1, Bh_c, z);
            float bcol[8];
#pragma unroll
            for (int r = 0; r < 8; ++r) bcol[r] = __builtin_fmaf(xxj_c, scn[r], c0a[r]);
#pragma unroll
            for (int r = 0; r < 8; ++r) {
                float a = (r < 4) ? a0[r] : a1[r - 4];
                float qf = __builtin_fmaf(a, sc2[r], bcol[r]);
                if (qf >= Tlo[r]) {
                    unsigned row = (unsigned)rowloc8[r];
                    if (qf >= Tin[r]) {
                        unsigned pos = atomicAdd(&outCnt[row], 1u);
                        outIdx[row][pos] = cp;
                    } else {
                        unsigned tp = atomicAdd(&tieCnt[row], 1u);
                        if (tp < 64u) tieIdx[row][tp] = cp;
                    }
                }
            }
            Bh_c = Bh_n; xxj_c = xxj_n;
        }
    }
    __syncthreads();

    // ---- resolve candidate window with exact fp32 scores (nt <= 64: 1 slot/lane) ----
#pragma unroll 1
    for (int rr = 0; rr < 8; ++rr) {
        int row = wv * 8 + rr;
        int gr = n0 + row;
        unsigned bA = outCnt[row];
        int need = 32 - (int)bA;
        if (need <= 0) continue;
        int nt = (int)tieCnt[row]; if (nt > 64) nt = 64;
        const float* xr = xt + (bbase + gr) * 32;
        float xxi_r = xxb[gr];
        float v0 = -INFINITY;
        int i0 = 0x7fffffff;
        bool a0v = lane < nt;
        if (a0v) {
            int c = (int)tieIdx[row][lane];
            const float* xc = xt + (bbase + c) * 32;
            float dot = 0.f;
#pragma unroll
            for (int ch = 0; ch < 32; ch += 4) {
                float4 rv = *(const float4*)(xr + ch);
                float4 cv = *(const float4*)(xc + ch);
                dot = __builtin_fmaf(rv.x, cv.x, dot);
                dot = __builtin_fmaf(rv.y, cv.y, dot);
                dot = __builtin_fmaf(rv.z, cv.z, dot);
                dot = __builtin_fmaf(rv.w, cv.w, dot);
            }
            v0 = 2.f * dot - xxi_r - xxb[c];
            i0 = c;
        }
        for (int it = 0; it < need; ++it) {
            float bvv = a0v ? v0 : -INFINITY;
            int bj2 = a0v ? i0 : 0x7fffffff;
#pragma unroll
            for (int off = 1; off < 64; off <<= 1) {
                float ov = __shfl_xor(bvv, off, 64);
                int oj = __shfl_xor(bj2, off, 64);
                if (ov > bvv || (ov == bvv && oj < bj2)) { bvv = ov; bj2 = oj; }
            }
            if (a0v && i0 == bj2) a0v = false;
            if (lane == 0) outIdx[row][bA + it] = (unsigned)bj2;
        }
    }
    __syncthreads();

    // ---- fused attention gather ----
    {
        int l32 = lane & 31;
        int hsel = lane >> 5;
        const char* KVb = (const char*)(KV + bbase * 64);
        unsigned laneoff = (unsigned)l32 * 8u;
#pragma unroll 1
        for (int rr = 0; rr < 4; ++rr) {
            int row = wv * 8 + rr * 2 + hsel;
            size_t gp = bbase + (size_t)(n0 + row);
            float q = Qf[gp * 32 + l32];
            int jv = (int)outIdx[row][l32];
            float zacc = 0.f, macc = 0.f;
#pragma unroll 8
            for (int k = 0; k < 32; ++k) {
                int j = __shfl(jv, k, 32);
                unsigned off = ((unsigned)j << 8) + laneoff;
                float2 kv = *(const float2*)(KVb + off);
                float s = q * kv.x;
                s += __shfl_xor(s, 1, 8);
                s += __shfl_xor(s, 2, 8);
                s += __shfl_xor(s, 4, 8);
                zacc += s;
                macc = __builtin_fmaf(s, kv.y, macc);
            }
            float Z = 1.f / (zacc + 1e-6f);
            msg[gp * 32 + l32] = macc * Z;
        }
    }
}

// ---------------- K5: merge + LN1 + MLP + LN2 + residual + transpose (MFMA) ----------------
__global__ __launch_bounds__(256, 2) void k_post(
        const float* __restrict__ msg, const float* __restrict__ xt,
        const float* __restrict__ w_merge,
        const float* __restrict__ ln1_g, const float* __restrict__ ln1_b,
        const float* __restrict__ w_mlp1, const float* __restrict__ w_mlp2,
        const float* __restrict__ ln2_g, const float* __restrict__ ln2_b,
        float* __restrict__ out) {
    __shared__ _Float16 wmT[2][32][32];
    __shared__ _Float16 w1T[2][64][64];
    __shared__ _Float16 w2T[2][32][64];
    __shared__ _Float16 sPh[4][16][40], sPl[4][16][40];
    __shared__ _Float16 sHh[4][16][72], sHl[4][16][72];
    int t = threadIdx.x;
    for (int i = t; i < 1024; i += 256) {
        float v = w_merge[i]; int in = i >> 5, o = i & 31;
        _Float16 h = (_Float16)v;
        wmT[0][o][in] = h; wmT[1][o][in] = (_Float16)(v - (float)h);
    }
    for (int i = t; i < 4096; i += 256) {
        float v = w_mlp1[i]; int in = i >> 6, o = i & 63;
        _Float16 h = (_Float16)v;
        w1T[0][o][in] = h; w1T[1][o][in] = (_Float16)(v - (float)h);
    }
    for (int i = t; i < 2048; i += 256) {
        float v = w_mlp2[i]; int in = i >> 5, o = i & 31;
        _Float16 h = (_Float16)v;
        w2T[0][o][in] = h; w2T[1][o][in] = (_Float16)(v - (float)h);
    }
    int wv = t >> 6, lane = t & 63;
    int row = lane & 15, kg = lane >> 4;
    int p0 = blockIdx.x * 64 + wv * 16;
    int b = p0 >> 12;
    float g1a = ln1_g[row], b1a = ln1_b[row], g1b = ln1_g[row + 16], b1b = ln1_b[row + 16];
    float g2a = ln2_g[row], b2a = ln2_b[row], g2b = ln2_g[row + 16], b2b = ln2_b[row + 16];
    __syncthreads();

    f32x4 z4 = {0.f, 0.f, 0.f, 0.f};
    f16x8 Amh, Aml;
    {
        const float* mr = msg + (size_t)(p0 + row) * 32 + kg * 8;
#pragma unroll
        for (int j = 0; j < 8; ++j) {
            float v = mr[j];
            _Float16 h = (_Float16)v;
            Amh[j] = h; Aml[j] = (_Float16)(v - (float)h);
        }
    }
    f32x4 accM[2];
#pragma unroll
    for (int n = 0; n < 2; ++n) {
        f16x8 Bh = *(const f16x8*)&wmT[0][n * 16 + row][kg * 8];
        f16x8 Bl = *(const f16x8*)&wmT[1][n * 16 + row][kg * 8];
        f32x4 a = z4;
        a = MFMA16(Aml, Bl, a); a = MFMA16(Amh, Bl, a);
        a = MFMA16(Aml, Bh, a); a = MFMA16(Amh, Bh, a);
        accM[n] = a;
    }
#pragma unroll
    for (int r = 0; r < 4; ++r) {
        float s0 = accM[0][r], s1 = accM[1][r];
        float sm = s0 + s1;
        sm += __shfl_xor(sm, 1, 64); sm += __shfl_xor(sm, 2, 64);
        sm += __shfl_xor(sm, 4, 64); sm += __shfl_xor(sm, 8, 64);
        float mean = sm * (1.f / 32.f);
        float d0 = s0 - mean, d1 = s1 - mean;
        float vv = d0 * d0 + d1 * d1;
        vv += __shfl_xor(vv, 1, 64); vv += __shfl_xor(vv, 2, 64);
        vv += __shfl_xor(vv, 4, 64); vv += __shfl_xor(vv, 8, 64);
        float rst = rsqrtf(vv * (1.f / 32.f) + 1e-5f);
        float m0 = g1a * d0 * rst + b1a;
        float m1 = g1b * d1 * rst + b1b;
        int pl = kg * 4 + r;
        _Float16 h0 = (_Float16)m0;
        sPh[wv][pl][row] = h0; sPl[wv][pl][row] = (_Float16)(m0 - (float)h0);
        _Float16 h1 = (_Float16)m1;
        sPh[wv][pl][row + 16] = h1; sPl[wv][pl][row + 16] = (_Float16)(m1 - (float)h1);
    }
    __syncthreads();
    f16x8 Axh, Axl;
    {
        const float* xr = xt + (size_t)(p0 + row) * 32 + kg * 8;
#pragma unroll
        for (int j = 0; j < 8; ++j) {
            float v = xr[j];
            _Float16 h = (_Float16)v;
            Axh[j] = h; Axl[j] = (_Float16)(v - (float)h);
        }
    }
    f16x8 Aph = *(const f16x8*)&sPh[wv][row][kg * 8];
    f16x8 Apl = *(const f16x8*)&sPl[wv][row][kg * 8];
    f32x4 accH[4];
#pragma unroll
    for (int n = 0; n < 4; ++n) {
        f16x8 B0h = *(const f16x8*)&w1T[0][n * 16 + row][kg * 8];
        f16x8 B0l = *(const f16x8*)&w1T[1][n * 16 + row][kg * 8];
        f16x8 B1h = *(const f16x8*)&w1T[0][n * 16 + row][32 + kg * 8];
        f16x8 B1l = *(const f16x8*)&w1T[1][n * 16 + row][32 + kg * 8];
        f32x4 a = z4;
        a = MFMA16(Axl, B0l, a); a = MFMA16(Axh, B0l, a);
        a = MFMA16(Axl, B0h, a); a = MFMA16(Axh, B0h, a);
        a = MFMA16(Apl, B1l, a); a = MFMA16(Aph, B1l, a);
        a = MFMA16(Apl, B1h, a); a = MFMA16(Aph, B1h, a);
        accH[n] = a;
    }
#pragma unroll
    for (int n = 0; n < 4; ++n) {
#pragma unroll
        for (int r = 0; r < 4; ++r) {
            float hv = fmaxf(accH[n][r], 0.f);
            int pl = kg * 4 + r;
            _Float16 hh = (_Float16)hv;
            sHh[wv][pl][n * 16 + row] = hh;
            sHl[wv][pl][n * 16 + row] = (_Float16)(hv - (float)hh);
        }
    }
    __syncthreads();
    f16x8 Hh0 = *(const f16x8*)&sHh[wv][row][kg * 8];
    f16x8 Hl0 = *(const f16x8*)&sHl[wv][row][kg * 8];
    f16x8 Hh1 = *(const f16x8*)&sHh[wv][row][32 + kg * 8];
    f16x8 Hl1 = *(const f16x8*)&sHl[wv][row][32 + kg * 8];
    f32x4 accO[2];
#pragma unroll
    for (int n = 0; n < 2; ++n) {
        f16x8 B0h = *(const f16x8*)&w2T[0][n * 16 + row][kg * 8];
        f16x8 B0l = *(const f16x8*)&w2T[1][n * 16 + row][kg * 8];
        f16x8 B1h = *(const f16x8*)&w2T[0][n * 16 + row][32 + kg * 8];
        f16x8 B1l = *(const f16x8*)&w2T[1][n * 16 + row][32 + kg * 8];
        f32x4 a = z4;
        a = MFMA16(Hl0, B0l, a); a = MFMA16(Hh0, B0l, a);
        a = MFMA16(Hl0, B0h, a); a = MFMA16(Hh0, B0h, a);
        a = MFMA16(Hl1, B1l, a); a = MFMA16(Hh1, B1l, a);
        a = MFMA16(Hl1, B1h, a); a = MFMA16(Hh1, B1h, a);
        accO[n] = a;
    }
#pragma unroll
    for (int r = 0; r < 4; ++r) {
        float s0 = accO[0][r], s1 = accO[1][r];
        float sm = s0 + s1;
        sm += __shfl_xor(sm, 1, 64); sm += __shfl_xor(sm, 2, 64);
        sm += __shfl_xor(sm, 4, 64); sm += __shfl_xor(sm, 8, 64);
        float mean = sm * (1.f / 32.f);
        float d0 = s0 - mean, d1 = s1 - mean;
        float vv = d0 * d0 + d1 * d1;
        vv += __shfl_xor(vv, 1, 64); vv += __shfl_xor(vv, 2, 64);
        vv += __shfl_xor(vv, 4, 64); vv += __shfl_xor(vv, 8, 64);
        float rst = rsqrtf(vv * (1.f / 32.f) + 1e-5f);
        float o0 = g2a * d0 * rst + b2a;
        float o1 = g2b * d1 * rst + b2b;
        int pt = p0 + kg * 4 + r;
        int nb = pt & 4095;
        float xv0 = xt[(size_t)pt * 32 + row];
        float xv1 = xt[(size_t)pt * 32 + row + 16];
        out[((size_t)b * 32 + row) * 4096 + nb] = xv0 + o0;
        out[((size_t)b * 32 + row + 16) * 4096 + nb] = xv1 + o1;
    }
}

extern "C" void kernel_launch(void* const* d_in, const int* in_sizes, int n_in,
                              void* d_out, int out_size, void* d_ws, size_t ws_size,
                              hipStream_t stream) {
    const float* feat   = (const float*)d_in[0];
    const float* xyz    = (const float*)d_in[1];
    const float* w_pos1 = (const float*)d_in[2];
    const float* b_pos1 = (const float*)d_in[3];
    const float* w_pos2 = (const float*)d_in[4];
    const float* b_pos2 = (const float*)d_in[5];
    const float* w_q    = (const float*)d_in[6];
    const float* w_k    = (const float*)d_in[7];
    const float* w_v    = (const float*)d_in[8];
    const float* w_mg   = (const float*)d_in[9];
    const float* ln1_g  = (const float*)d_in[10];
    const float* ln1_b  = (const float*)d_in[11];
    const float* w_mlp1 = (const float*)d_in[12];
    const float* w_mlp2 = (const float*)d_in[13];
    const float* ln2_g  = (const float*)d_in[14];
    const float* ln2_b  = (const float*)d_in[15];
    float* ws = (float*)d_ws;
    float* xt = ws + OFF_XT;
    float* Qf = ws + OFF_QF;
    float* KVp = ws + OFF_KV;
    float* xx = ws + OFF_XX;
    _Float16* Xh = (_Float16*)(ws + OFF_XH);
    float* msg = ws + OFF_MSG;
    float* out = (float*)d_out;

    k_tp<<<dim3(64, 8), 256, 0, stream>>>(feat, xyz, w_pos1, b_pos1, w_pos2, b_pos2,
                                          w_q, w_k, w_v, xt, Xh, xx, Qf, KVp);
    k_knn<<<1024, 256, 0, stream>>>(Xh, xt, xx, Qf, KVp, msg);
    k_post<<<512, 256, 0, stream>>>(msg, xt, w_mg, ln1_g, ln1_b,
                                    w_mlp1, w_mlp2, ln2_g, ln2_b, out);
}

// Round 21
// 220.370 us; speedup vs baseline: 1.0598x; 1.0018x over previous
//
#include <hip/hip_runtime.h>
#include <math.h>

#define BB 8
#define CC 32
#define NN 4096
#define KNN 32
#define NP (BB*NN)   // 32768

// workspace float offsets
#define OFF_XT  0u
#define OFF_QF  1048576u
#define OFF_KV  2097152u   // 2M floats: 32 x float2 per point
#define OFF_XX  4194304u
#define OFF_XH  5275648u   // 1M f16
#define OFF_MSG 5799936u   // 1M floats

typedef _Float16 f16x8 __attribute__((ext_vector_type(8)));
typedef float f32x4 __attribute__((ext_vector_type(4)));
#define MFMA16(A,B,C) __builtin_amdgcn_mfma_f32_16x16x32_f16(A,B,C,0,0,0)

__device__ __forceinline__ float elu1(float x) {
    return x > 0.f ? x + 1.f : expf(x);
}

// ---------------- K1: fused transpose + prep ----------------
__global__ __launch_bounds__(256) void k_tp(
        const float* __restrict__ feat, const float* __restrict__ xyz,
        const float* __restrict__ w_pos1, const float* __restrict__ b_pos1,
        const float* __restrict__ w_pos2, const float* __restrict__ b_pos2,
        const float* __restrict__ w_q, const float* __restrict__ w_k,
        const float* __restrict__ w_v,
        float* __restrict__ xt, _Float16* __restrict__ Xh,
        float* __restrict__ xx,
        float* __restrict__ Qf, float* __restrict__ KV) {
    __shared__ float tile[32][65];
    __shared__ float sW2[1024], sWq[1024], sWk[1024], sWv[1024];
    int b = blockIdx.y;
    int n0 = blockIdx.x * 64;
    int t = threadIdx.x;

    for (int i = t; i < 1024; i += 256) {
        sW2[i] = w_pos2[i];
        sWq[i] = w_q[i];
        sWk[i] = w_k[i];
        sWv[i] = w_v[i];
    }
    int lane = t & 31;
    float w1c0 = w_pos1[lane], w1c1 = w_pos1[32 + lane], w1c2 = w_pos1[64 + lane];
    float b1c = b_pos1[lane], b2c = b_pos2[lane];

    int nn = t & 63, cr = t >> 6;
#pragma unroll
    for (int r = 0; r < 8; ++r) {
        int c = r * 4 + cr;
        tile[c][nn] = feat[((size_t)b * 32 + c) * NN + n0 + nn];
    }
    __syncthreads();

    int c2 = t & 31, nr = t >> 5;
#pragma unroll
    for (int r = 0; r < 8; ++r) {
        int nl = r * 8 + nr;
        size_t gi = ((size_t)b * NN + n0 + nl) * 32 + c2;
        float v = tile[c2][nl];
        xt[gi] = v;
        Xh[gi] = (_Float16)v;
    }
    if (t < 64) {
        float s = 0.f;
#pragma unroll
        for (int c = 0; c < 32; ++c) { float u = tile[c][t]; s += u * u; }
        xx[(size_t)b * NN + n0 + t] = s;
    }

    int g = t >> 5;
#pragma unroll 1
    for (int pp = g; pp < 64; pp += 8) {
        asm volatile("" ::: "memory");
        size_t p = (size_t)b * NN + n0 + pp;
        float x0 = xyz[p * 3 + 0];
        float x1 = xyz[p * 3 + 1];
        float x2 = xyz[p * 3 + 2];
        float h = fmaxf(x0 * w1c0 + x1 * w1c1 + x2 * w1c2 + b1c, 0.f);
        float P = b2c;
#pragma unroll 8
        for (int j = 0; j < 32; ++j) P += __shfl(h, j, 32) * sW2[j * 32 + lane];
        float xv = tile[lane][pp];
        float qin = xv + P;
        float qa = 0.f, ka = 0.f, va = 0.f;
#pragma unroll 8
        for (int j = 0; j < 32; ++j) {
            float qj = __shfl(qin, j, 32);
            qa += qj * sWq[j * 32 + lane];
            ka += qj * sWk[j * 32 + lane];
            va += qj * sWv[j * 32 + lane];
        }
        Qf[p * 32 + lane] = elu1(qa);
        float2 kvv;
        kvv.x = elu1(ka);
        kvv.y = va;   // raw V ((V/k)*k cancels exactly)
        *(((float2*)(KV + p * 64)) + lane) = kvv;
    }
}

// ---------------- K3: KNN + fused attention gather ----------
__global__ __launch_bounds__(256, 4) void k_knn(
        const _Float16* __restrict__ Xh,
        const float* __restrict__ xt, const float* __restrict__ xx,
        const float* __restrict__ Qf, const float* __restrict__ KV,
        float* __restrict__ msg) {
    __shared__ unsigned histU[32 * 132];
    __shared__ unsigned outIdx[32][32];
    __shared__ unsigned tieIdx[32][64];
    __shared__ int sT[32];
    __shared__ float sFloor[32];
    __shared__ unsigned outCnt[32], tieCnt[32];
    __shared__ float sM2;
    __shared__ float redbuf[4];

    int bid = blockIdx.x;
    int b = bid & 7;                 // XCD swizzle: batch per XCD
    int n0 = (bid >> 3) << 5;        // 32 rows per block
    int t = threadIdx.x;
    int lane = t & 63, wv = t >> 6;
    size_t bbase = (size_t)b * NN;

    for (int i = t; i < 32 * 132; i += 256) histU[i] = 0u;
    if (t < 32) { outCnt[t] = 0u; tieCnt[t] = 0u; }

    float lm = 0.f;
    for (int i = t; i < NN; i += 256) lm = fmaxf(lm, xx[bbase + i]);
#pragma unroll
    for (int off = 32; off >= 1; off >>= 1) lm = fmaxf(lm, __shfl_xor(lm, off, 64));
    if (lane == 0) redbuf[wv] = lm;
    __syncthreads();
    if (t == 0) sM2 = fmaxf(fmaxf(redbuf[0], redbuf[1]), fmaxf(redbuf[2], redbuf[3]));
    __syncthreads();
    float M2 = sM2;

    int al = lane & 15;
    int kgrp = lane >> 4;
    int ak = kgrp * 8;
    const _Float16* Xhb = Xh + bbase * 32;
    const float* xxb = xx + bbase;
    f16x8 Ah0 = *(const f16x8*)(Xhb + (size_t)(n0 + al) * 32 + ak);
    f16x8 Ah1 = *(const f16x8*)(Xhb + (size_t)(n0 + 16 + al) * 32 + ak);

    const float C127 = 127.99f;
    float sc2[8], scn[8], c0a[8];
    unsigned rowW[8];
    int rowloc8[8];
#pragma unroll
    for (int r = 0; r < 8; ++r) {
        int rowloc = (r < 4 ? 0 : 16) + kgrp * 4 + (r & 3);
        float xxi = xxb[n0 + rowloc];
        float scale = C127 / (2.f * (xxi + M2));
        sc2[r] = scale + scale;
        scn[r] = -scale;
        c0a[r] = __builtin_fmaf(-xxi, scale, C127);
        rowW[r] = (unsigned)rowloc * 132u;
        rowloc8[r] = rowloc;
    }

    unsigned cp0 = (unsigned)(wv * 1024 + al);
    unsigned akB = (unsigned)ak * 2u;
    const char* XhbB = (const char*)Xhb;
    const f32x4 z = {0.f, 0.f, 0.f, 0.f};

    // ---- phase A: full histogram of first 8 tiles (512-col sample) ----
#pragma unroll 1
    for (int tt = 0; tt < 8; ++tt) {
        unsigned cp = cp0 + (unsigned)(tt << 4);
        f16x8 Bh = *(const f16x8*)(XhbB + cp * 64u + akB);
        float xxj = xxb[cp];
        f32x4 a0 = MFMA16(Ah0, Bh, z);
        f32x4 a1 = MFMA16(Ah1, Bh, z);
#pragma unroll
        for (int r = 0; r < 8; ++r) {
            float a = (r < 4) ? a0[r] : a1[r - 4];
            float bcol = __builtin_fmaf(xxj, scn[r], c0a[r]);
            float qf = __builtin_fmaf(a, sc2[r], bcol);
            float qc = __builtin_amdgcn_fmed3f(qf, 0.f, C127);
            atomicAdd(&histU[rowW[r] + (unsigned)qc], 1u);
        }
    }
    __syncthreads();

    // ---- floor scan: per-row 32nd-best bucket of the sample ----
#pragma unroll 1
    for (int rr = 0; rr < 8; ++rr) {
        int row = wv * 8 + rr;
        const unsigned* Hr = histU + row * 132;
        unsigned cl = Hr[2 * lane], ch = Hr[2 * lane + 1];
        unsigned ss = cl + ch;
        unsigned acc = ss;
#pragma unroll
        for (int off = 1; off < 64; off <<= 1) {
            unsigned vv = __shfl_down(acc, off, 64);
            if (lane + off < 64) acc += vv;
        }
        unsigned run = acc - ss;
        int Tl = -1;
        if (run < 32u && run + ch >= 32u) Tl = 2 * lane + 1;
        run += ch;
        if (Tl < 0 && run < 32u && run + cl >= 32u) Tl = 2 * lane;
        unsigned long long bal = __ballot(Tl >= 0);
        int src = __ffsll(bal) - 1;
        int Tv = __shfl(Tl, src, 64);
        if (lane == 0) sFloor[row] = (Tv <= 0) ? -3.0e38f : (float)Tv;
    }
    __syncthreads();

    float fb1[8];
#pragma unroll
    for (int r = 0; r < 8; ++r) fb1[r] = sFloor[rowloc8[r]];

    // ---- phase B: filtered histogram of tiles 8..63 (pipelined) ----
    {
        unsigned cpc = cp0 + (8u << 4);
        f16x8 Bh_c = *(const f16x8*)(XhbB + cpc * 64u + akB);
        float xxj_c = xxb[cpc];
#pragma unroll 1
        for (int tt = 8; tt < 64; ++tt) {
            int tn = (tt + 1 < 64) ? (tt + 1) : 8;
            unsigned cpn = cp0 + (unsigned)(tn << 4);
            f16x8 Bh_n = *(const f16x8*)(XhbB + cpn * 64u + akB);
            float xxj_n = xxb[cpn];
            f32x4 a0 = MFMA16(Ah0, Bh_c, z);
            f32x4 a1 = MFMA16(Ah1, Bh_c, z);
            float bcol[8];
#pragma unroll
            for (int r = 0; r < 8; ++r) bcol[r] = __builtin_fmaf(xxj_c, scn[r], c0a[r]);
#pragma unroll
            for (int r = 0; r < 8; ++r) {
                float a = (r < 4) ? a0[r] : a1[r - 4];
                float qf = __builtin_fmaf(a, sc2[r], bcol[r]);
                if (qf >= fb1[r]) {
                    float qc = __builtin_amdgcn_fmed3f(qf, 0.f, C127);
                    atomicAdd(&histU[rowW[r] + (unsigned)qc], 1u);
                }
            }
            Bh_c = Bh_n; xxj_c = xxj_n;
        }
    }
    __syncthreads();

    // ---- final scan: per-row suffix over 128 buckets -> T ----
#pragma unroll 1
    for (int rr = 0; rr < 8; ++rr) {
        int row = wv * 8 + rr;
        const unsigned* Hr = histU + row * 132;
        unsigned cl = Hr[2 * lane], ch = Hr[2 * lane + 1];
        unsigned ss = cl + ch;
        unsigned acc = ss;
#pragma unroll
        for (int off = 1; off < 64; off <<= 1) {
            unsigned vv = __shfl_down(acc, off, 64);
            if (lane + off < 64) acc += vv;
        }
        unsigned run = acc - ss;
        int Tl = -1;
        if (run < 32u && run + ch >= 32u) Tl = 2 * lane + 1;
        run += ch;
        if (Tl < 0 && run < 32u && run + cl >= 32u) Tl = 2 * lane;
        unsigned long long bal = __ballot(Tl >= 0);
        int src = __ffsll(bal) - 1;
        int Tv = __shfl(Tl, src, 64);
        if (lane == 0) sT[row] = Tv;
    }
    __syncthreads();

    // margin thresholds: certain qf >= T+1+m; candidate qf >= T-m (m = 0.1875 >= 3*eps)
    float Tin[8], Tlo[8];
#pragma unroll
    for (int r = 0; r < 8; ++r) {
        int T = sT[rowloc8[r]];
        Tin[r] = (float)(T + 1) + 0.1875f;
        Tlo[r] = (T == 0) ? -3.0e38f : ((float)T - 0.1875f);
    }

    // ---- sweep 2: identical qf recompute, margin-window emit ----
    {
        f16x8 Bh_c = *(const f16x8*)(XhbB + cp0 * 64u + akB);
        float xxj_c = xxb[cp0];
#pragma unroll 1
        for (int tt = 0; tt < 64; ++tt) {
            unsigned cp = cp0 + (unsigned)(tt << 4);
            unsigned cpn = cp0 + (unsigned)(((tt + 1) & 63) << 4);
            f16x8 Bh_n = *(const f16x8*)(XhbB + cpn * 64u + akB);
            float xxj_n = xxb[cpn];
            f32x4 a0 = MFMA16(Ah0, Bh_c, z);
            f32x4 a1 = MFMA16(Ah1, Bh_c, z);
            float bcol[8];
#pragma unroll
            for (int r = 0; r < 8; ++r) bcol[r] = __builtin_fmaf(xxj_c, scn[r], c0a[r]);
#pragma unroll
            for (int r = 0; r < 8; ++r) {
                float a = (r < 4) ? a0[r] : a1[r - 4];
                float qf = __builtin_fmaf(a, sc2[r], bcol[r]);
                if (qf >= Tlo[r]) {
                    unsigned row = (unsigned)rowloc8[r];
                    if (qf >= Tin[r]) {
                        unsigned pos = atomicAdd(&outCnt[row], 1u);
                        outIdx[row][pos] = cp;
                    } else {
                        unsigned tp = atomicAdd(&tieCnt[row], 1u);
                        if (tp < 64u) tieIdx[row][tp] = cp;
                    }
                }
            }
            Bh_c = Bh_n; xxj_c = xxj_n;
        }
    }
    __syncthreads();

    // ---- resolve candidate window with exact fp32 scores (nt <= 64: 1 slot/lane) ----
#pragma unroll 1
    for (int rr = 0; rr < 8; ++rr) {
        int row = wv * 8 + rr;
        int gr = n0 + row;
        unsigned bA = outCnt[row];
        int need = 32 - (int)bA;
        if (need <= 0) continue;
        int nt = (int)tieCnt[row]; if (nt > 64) nt = 64;
        const float* xr = xt + (bbase + gr) * 32;
        float xxi_r = xxb[gr];
        float v0 = -INFINITY;
        int i0 = 0x7fffffff;
        bool a0v = lane < nt;
        if (a0v) {
            int c = (int)tieIdx[row][lane];
            const float* xc = xt + (bbase + c) * 32;
            float dot = 0.f;
#pragma unroll
            for (int ch = 0; ch < 32; ch += 4) {
                float4 rv = *(const float4*)(xr + ch);
                float4 cv = *(const float4*)(xc + ch);
                dot = __builtin_fmaf(rv.x, cv.x, dot);
                dot = __builtin_fmaf(rv.y, cv.y, dot);
                dot = __builtin_fmaf(rv.z, cv.z, dot);
                dot = __builtin_fmaf(rv.w, cv.w, dot);
            }
            v0 = 2.f * dot - xxi_r - xxb[c];
            i0 = c;
        }
        for (int it = 0; it < need; ++it) {
            float bvv = a0v ? v0 : -INFINITY;
            int bj2 = a0v ? i0 : 0x7fffffff;
#pragma unroll
            for (int off = 1; off < 64; off <<= 1) {
                float ov = __shfl_xor(bvv, off, 64);
                int oj = __shfl_xor(bj2, off, 64);
                if (ov > bvv || (ov == bvv && oj < bj2)) { bvv = ov; bj2 = oj; }
            }
            if (a0v && i0 == bj2) a0v = false;
            if (lane == 0) outIdx[row][bA + it] = (unsigned)bj2;
        }
    }
    __syncthreads();

    // ---- fused attention gather ----
    {
        int l32 = lane & 31;
        int hsel = lane >> 5;
        const char* KVb = (const char*)(KV + bbase * 64);
        unsigned laneoff = (unsigned)l32 * 8u;
#pragma unroll 1
        for (int rr = 0; rr < 4; ++rr) {
            int row = wv * 8 + rr * 2 + hsel;
            size_t gp = bbase + (size_t)(n0 + row);
            float q = Qf[gp * 32 + l32];
            int jv = (int)outIdx[row][l32];
            float zacc = 0.f, macc = 0.f;
#pragma unroll 8
            for (int k = 0; k < 32; ++k) {
                int j = __shfl(jv, k, 32);
                unsigned off = ((unsigned)j << 8) + laneoff;
                float2 kv = *(const float2*)(KVb + off);
                float s = q * kv.x;
                s += __shfl_xor(s, 1, 8);
                s += __shfl_xor(s, 2, 8);
                s += __shfl_xor(s, 4, 8);
                zacc += s;
                macc = __builtin_fmaf(s, kv.y, macc);
            }
            float Z = 1.f / (zacc + 1e-6f);
            msg[gp * 32 + l32] = macc * Z;
        }
    }
}

// ---------------- K5: merge + LN1 + MLP + LN2 + residual + transpose (MFMA) ----------------
__global__ __launch_bounds__(256, 2) void k_post(
        const float* __restrict__ msg, const float* __restrict__ xt,
        const float* __restrict__ w_merge,
        const float* __restrict__ ln1_g, const float* __restrict__ ln1_b,
        const float* __restrict__ w_mlp1, const float* __restrict__ w_mlp2,
        const float* __restrict__ ln2_g, const float* __restrict__ ln2_b,
        float* __restrict__ out) {
    __shared__ _Float16 wmT[2][32][32];
    __shared__ _Float16 w1T[2][64][64];
    __shared__ _Float16 w2T[2][32][64];
    __shared__ _Float16 sPh[4][16][40], sPl[4][16][40];
    __shared__ _Float16 sHh[4][16][72], sHl[4][16][72];
    int t = threadIdx.x;
    for (int i = t; i < 1024; i += 256) {
        float v = w_merge[i]; int in = i >> 5, o = i & 31;
        _Float16 h = (_Float16)v;
        wmT[0][o][in] = h; wmT[1][o][in] = (_Float16)(v - (float)h);
    }
    for (int i = t; i < 4096; i += 256) {
        float v = w_mlp1[i]; int in = i >> 6, o = i & 63;
        _Float16 h = (_Float16)v;
        w1T[0][o][in] = h; w1T[1][o][in] = (_Float16)(v - (float)h);
    }
    for (int i = t; i < 2048; i += 256) {
        float v = w_mlp2[i]; int in = i >> 5, o = i & 31;
        _Float16 h = (_Float16)v;
        w2T[0][o][in] = h; w2T[1][o][in] = (_Float16)(v - (float)h);
    }
    int wv = t >> 6, lane = t & 63;
    int row = lane & 15, kg = lane >> 4;
    int p0 = blockIdx.x * 64 + wv * 16;
    int b = p0 >> 12;
    float g1a = ln1_g[row], b1a = ln1_b[row], g1b = ln1_g[row + 16], b1b = ln1_b[row + 16];
    float g2a = ln2_g[row], b2a = ln2_b[row], g2b = ln2_g[row + 16], b2b = ln2_b[row + 16];
    __syncthreads();

    f32x4 z4 = {0.f, 0.f, 0.f, 0.f};
    f16x8 Amh, Aml;
    {
        const float* mr = msg + (size_t)(p0 + row) * 32 + kg * 8;
#pragma unroll
        for (int j = 0; j < 8; ++j) {
            float v = mr[j];
            _Float16 h = (_Float16)v;
            Amh[j] = h; Aml[j] = (_Float16)(v - (float)h);
        }
    }
    f32x4 accM[2];
#pragma unroll
    for (int n = 0; n < 2; ++n) {
        f16x8 Bh = *(const f16x8*)&wmT[0][n * 16 + row][kg * 8];
        f16x8 Bl = *(const f16x8*)&wmT[1][n * 16 + row][kg * 8];
        f32x4 a = z4;
        a = MFMA16(Aml, Bl, a); a = MFMA16(Amh, Bl, a);
        a = MFMA16(Aml, Bh, a); a = MFMA16(Amh, Bh, a);
        accM[n] = a;
    }
#pragma unroll
    for (int r = 0; r < 4; ++r) {
        float s0 = accM[0][r], s1 = accM[1][r];
        float sm = s0 + s1;
        sm += __shfl_xor(sm, 1, 64); sm += __shfl_xor(sm, 2, 64);
        sm += __shfl_xor(sm, 4, 64); sm += __shfl_xor(sm, 8, 64);
        float mean = sm * (1.f / 32.f);
        float d0 = s0 - mean, d1 = s1 - mean;
        float vv = d0 * d0 + d1 * d1;
        vv += __shfl_xor(vv, 1, 64); vv += __shfl_xor(vv, 2, 64);
        vv += __shfl_xor(vv, 4, 64); vv += __shfl_xor(vv, 8, 64);
        float rst = rsqrtf(vv * (1.f / 32.f) + 1e-5f);
        float m0 = g1a * d0 * rst + b1a;
        float m1 = g1b * d1 * rst + b1b;
        int pl = kg * 4 + r;
        _Float16 h0 = (_Float16)m0;
        sPh[wv][pl][row] = h0; sPl[wv][pl][row] = (_Float16)(m0 - (float)h0);
        _Float16 h1 = (_Float16)m1;
        sPh[wv][pl][row + 16] = h1; sPl[wv][pl][row + 16] = (_Float16)(m1 - (float)h1);
    }
    __syncthreads();
    f16x8 Axh, Axl;
    {
        const float* xr = xt + (size_t)(p0 + row) * 32 + kg * 8;
#pragma unroll
        for (int j = 0; j < 8; ++j) {
            float v = xr[j];
            _Float16 h = (_Float16)v;
            Axh[j] = h; Axl[j] = (_Float16)(v - (float)h);
        }
    }
    f16x8 Aph = *(const f16x8*)&sPh[wv][row][kg * 8];
    f16x8 Apl = *(const f16x8*)&sPl[wv][row][kg * 8];
    f32x4 accH[4];
#pragma unroll
    for (int n = 0; n < 4; ++n) {
        f16x8 B0h = *(const f16x8*)&w1T[0][n * 16 + row][kg * 8];
        f16x8 B0l = *(const f16x8*)&w1T[1][n * 16 + row][kg * 8];
        f16x8 B1h = *(const f16x8*)&w1T[0][n * 16 + row][32 + kg * 8];
        f16x8 B1l = *(const f16x8*)&w1T[1][n * 16 + row][32 + kg * 8];
        f32x4 a = z4;
        a = MFMA16(Axl, B0l, a); a = MFMA16(Axh, B0l, a);
        a = MFMA16(Axl, B0h, a); a = MFMA16(Axh, B0h, a);
        a = MFMA16(Apl, B1l, a); a = MFMA16(Aph, B1l, a);
        a = MFMA16(Apl, B1h, a); a = MFMA16(Aph, B1h, a);
        accH[n] = a;
    }
#pragma unroll
    for (int n = 0; n < 4; ++n) {
#pragma unroll
        for (int r = 0; r < 4; ++r) {
            float hv = fmaxf(accH[n][r], 0.f);
            int pl = kg * 4 + r;
            _Float16 hh = (_Float16)hv;
            sHh[wv][pl][n * 16 + row] = hh;
            sHl[wv][pl][n * 16 + row] = (_Float16)(hv - (float)hh);
        }
    }
    __syncthreads();
    f16x8 Hh0 = *(const f16x8*)&sHh[wv][row][kg * 8];
    f16x8 Hl0 = *(const f16x8*)&sHl[wv][row][kg * 8];
    f16x8 Hh1 = *(const f16x8*)&sHh[wv][row][32 + kg * 8];
    f16x8 Hl1 = *(const f16x8*)&sHl[wv][row][32 + kg * 8];
    f32x4 accO[2];
#pragma unroll
    for (int n = 0; n < 2; ++n) {
        f16x8 B0h = *(const f16x8*)&w2T[0][n * 16 + row][kg * 8];
        f16x8 B0l = *(const f16x8*)&w2T[1][n * 16 + row][kg * 8];
        f16x8 B1h = *(const f16x8*)&w2T[0][n * 16 + row][32 + kg * 8];
        f16x8 B1l = *(const f16x8*)&w2T[1][n * 16 + row][32 + kg * 8];
        f32x4 a = z4;
        a = MFMA16(Hl0, B0l, a); a = MFMA16(Hh0, B0l, a);
        a = MFMA16(Hl0, B0h, a); a = MFMA16(Hh0, B0h, a);
        a = MFMA16(Hl1, B1l, a); a = MFMA16(Hh1, B1l, a);
        a = MFMA16(Hl1, B1h, a); a = MFMA16(Hh1, B1h, a);
        accO[n] = a;
    }
#pragma unroll
    for (int r = 0; r < 4; ++r) {
        float s0 = accO[0][r], s1 = accO[1][r];
        float sm = s0 + s1;
        sm += __shfl_xor(sm, 1, 64); sm += __shfl_xor(sm, 2, 64);
        sm += __shfl_xor(sm, 4, 64); sm += __shfl_xor(sm, 8, 64);
        float mean = sm * (1.f / 32.f);
        float d0 = s0 - mean, d1 = s1 - mean;
        float vv = d0 * d0 + d1 * d1;
        vv += __shfl_xor(vv, 1, 64); vv += __shfl_xor(vv, 2, 64);
        vv += __shfl_xor(vv, 4, 64); vv += __shfl_xor(vv, 8, 64);
        float rst = rsqrtf(vv * (1.f / 32.f) + 1e-5f);
        float o0 = g2a * d0 * rst + b2a;
        float o1 = g2b * d1 * rst + b2b;
        int pt = p0 + kg * 4 + r;
        int nb = pt & 4095;
        float xv0 = xt[(size_t)pt * 32 + row];
        float xv1 = xt[(size_t)pt * 32 + row + 16];
        out[((size_t)b * 32 + row) * 4096 + nb] = xv0 + o0;
        out[((size_t)b * 32 + row + 16) * 4096 + nb] = xv1 + o1;
    }
}

extern "C" void kernel_launch(void* const* d_in, const int* in_sizes, int n_in,
                              void* d_out, int out_size, void* d_ws, size_t ws_size,
                              hipStream_t stream) {
    const float* feat   = (const float*)d_in[0];
    const float* xyz    = (const float*)d_in[1];
    const float* w_pos1 = (const float*)d_in[2];
    const float* b_pos1 = (const float*)d_in[3];
    const float* w_pos2 = (const float*)d_in[4];
    const float* b_pos2 = (const float*)d_in[5];
    const float* w_q    = (const float*)d_in[6];
    const float* w_k    = (const float*)d_in[7];
    const float* w_v    = (const float*)d_in[8];
    const float* w_mg   = (const float*)d_in[9];
    const float* ln1_g  = (const float*)d_in[10];
    const float* ln1_b  = (const float*)d_in[11];
    const float* w_mlp1 = (const float*)d_in[12];
    const float* w_mlp2 = (const float*)d_in[13];
    const float* ln2_g  = (const float*)d_in[14];
    const float* ln2_b  = (const float*)d_in[15];
    float* ws = (float*)d_ws;
    float* xt = ws + OFF_XT;
    float* Qf = ws + OFF_QF;
    float* KVp = ws + OFF_KV;
    float* xx = ws + OFF_XX;
    _Float16* Xh = (_Float16*)(ws + OFF_XH);
    float* msg = ws + OFF_MSG;
    float* out = (float*)d_out;

    k_tp<<<dim3(64, 8), 256, 0, stream>>>(feat, xyz, w_pos1, b_pos1, w_pos2, b_pos2,
                                          w_q, w_k, w_v, xt, Xh, xx, Qf, KVp);
    k_knn<<<1024, 256, 0, stream>>>(Xh, xt, xx, Qf, KVp, msg);
    k_post<<<512, 256, 0, stream>>>(msg, xt, w_mg, ln1_g, ln1_b,
                                    w_mlp1, w_mlp2, ln2_g, ln2_b, out);
}